// Round 1
// baseline (1060.299 us; speedup 1.0000x reference)
//
#include <hip/hip_runtime.h>
#include <math.h>

// CriticBatchNet: NNConv(+edge-net) + GRU x6, Set2Set x6, LSTM head.
// Key restructure: msg[e] = out[src]@W_e[e] with W_e[e]=hidden[e]@e_w2+b2
//   => segsum_dst(msg)[m,f] = sum_kd S[m,kd]*V[kd,f],
//      S[m,k*32+d] = sum_{e:dst=m} hidden[e,k]*out[src_e,d]  (outer products)
//      S[m,1024+j] = sum_{e:dst=m} out[src_e,j]              (bias rows)
// so W_e (491MB) is never materialized and no float atomics are needed.

#define DD 32

__device__ __forceinline__ float sigf(float x){ return 1.f/(1.f+expf(-x)); }

__global__ void k_init(int* __restrict__ counts, int* __restrict__ cursor, int N){
  int i = blockIdx.x*blockDim.x + threadIdx.x;
  if (i < N){ counts[i]=0; cursor[i]=0; }
}

__global__ void k_lin0(const float* __restrict__ x, const float* __restrict__ w,
                       const float* __restrict__ b, float* __restrict__ cur, int N){
  int i = blockIdx.x*blockDim.x + threadIdx.x;
  if (i >= N*32) return;
  int n = i>>5, d = i&31;
  float acc = b[d];
  acc = fmaf(x[n*3+0], w[0*32+d], acc);
  acc = fmaf(x[n*3+1], w[1*32+d], acc);
  acc = fmaf(x[n*3+2], w[2*32+d], acc);
  cur[i] = fmaxf(acc, 0.f);
}

__global__ void k_hidden(const float* __restrict__ ea, const float* __restrict__ w,
                         const float* __restrict__ b, float* __restrict__ hid, int E){
  int i = blockIdx.x*blockDim.x + threadIdx.x;
  if (i >= E*32) return;
  int e = i>>5, k = i&31;
  float acc = b[k];
  #pragma unroll
  for (int j=0;j<4;++j) acc = fmaf(ea[e*4+j], w[j*32+k], acc);
  hid[i] = fmaxf(acc, 0.f);
}

__global__ void k_count(const int* __restrict__ dst, int* __restrict__ counts, int E){
  int i = blockIdx.x*blockDim.x + threadIdx.x;
  if (i < E) atomicAdd(&counts[dst[i]], 1);
}

// single-block exclusive scan of counts[N] -> row_off[N+1]
__global__ void k_scan(const int* __restrict__ counts, int* __restrict__ row_off, int N){
  __shared__ int buf[256];
  __shared__ int carry;
  int t = threadIdx.x;
  if (t == 0) carry = 0;
  __syncthreads();
  for (int base = 0; base < N; base += 256){
    int v = (base + t < N) ? counts[base + t] : 0;
    buf[t] = v; __syncthreads();
    for (int off = 1; off < 256; off <<= 1){
      int tmp = (t >= off) ? buf[t-off] : 0;
      __syncthreads();
      buf[t] += tmp;
      __syncthreads();
    }
    if (base + t < N) row_off[base + t] = carry + buf[t] - v;
    __syncthreads();
    if (t == 255) carry += buf[255];
    __syncthreads();
  }
  if (t == 0) row_off[N] = carry;
}

__global__ void k_scatter(const int* __restrict__ dst, const int* __restrict__ row_off,
                          int* __restrict__ cursor, int* __restrict__ eid, int E){
  int i = blockIdx.x*blockDim.x + threadIdx.x;
  if (i < E){
    int dn = dst[i];
    int pos = row_off[dn] + atomicAdd(&cursor[dn], 1);
    eid[pos] = i;
  }
}

// Vr[kd*32+f]: kd<1024 -> e_w2[(kd>>5)*1024 + (kd&31)*32 + f] ; else e_b2[(kd-1024)*32+f]
__global__ void k_permW2(const float* __restrict__ e_w2, const float* __restrict__ e_b2,
                         float* __restrict__ Vr){
  int idx = blockIdx.x*blockDim.x + threadIdx.x;
  if (idx >= 1056*32) return;
  int f = idx & 31, kd = idx >> 5;
  Vr[idx] = (kd < 1024) ? e_w2[(kd>>5)*1024 + (kd&31)*32 + f]
                        : e_b2[(kd-1024)*32 + f];
}

// one wave per node: accumulate S row (1056 f32) from in-edges
__global__ __launch_bounds__(256) void k_S(
    const int* __restrict__ row_off, const int* __restrict__ eid,
    const int* __restrict__ src, const float* __restrict__ hid,
    const float* __restrict__ cur, float* __restrict__ S, int N){
  int wave = (blockIdx.x*256 + threadIdx.x) >> 6;
  if (wave >= N) return;
  int l = threadIdx.x & 63;
  int d = l & 31, hiL = l >> 5;
  int lo = row_off[wave], hi = row_off[wave+1];
  float acc[16];
  #pragma unroll
  for (int r=0;r<16;++r) acc[r]=0.f;
  float aex = 0.f;
  for (int p = lo; p < hi; ++p){
    int e = eid[p];
    int s = src[e];
    float h_own = hid[e*32 + d];
    float o_own = cur[s*32 + d];
    #pragma unroll
    for (int r=0;r<16;++r){
      float hk = __shfl(h_own, 2*r + hiL, 64); // hidden[e][2r+hiL]
      acc[r] = fmaf(hk, o_own, acc[r]);        // S[kd], kd=r*64+l => k=2r+hiL, d=l&31
    }
    aex += o_own;
  }
  int base = wave*1056;
  #pragma unroll
  for (int r=0;r<16;++r) S[base + r*64 + l] = acc[r];
  if (l < 32) S[base + 1024 + l] = aex;
}

// m[n,f] = relu( (sum_kd S[n,kd]*Vr[kd,f])/deg + sum_k cur[n,k]*root_w[k,f] + conv_b[f] )
__global__ __launch_bounds__(256) void k_aggr_m(
    const float* __restrict__ S, const float* __restrict__ Vr,
    const float* __restrict__ cur, const float* __restrict__ root_w,
    const float* __restrict__ conv_b, const int* __restrict__ counts,
    float* __restrict__ m, int N){
  __shared__ float s_lds[8*1056];
  int nb = blockIdx.x*8;
  int t = threadIdx.x;
  const float4* S4 = (const float4*)S;
  float4* L4 = (float4*)s_lds;
  for (int i = t; i < 8*264; i += 256){
    int node = nb + i/264;
    L4[i] = (node < N) ? S4[node*264 + (i%264)] : make_float4(0,0,0,0);
  }
  __syncthreads();
  int sub = t >> 5, f = t & 31;
  int n = nb + sub;
  if (n >= N) return;
  const float* sp = &s_lds[sub*1056];
  float acc = 0.f;
  #pragma unroll 8
  for (int kd = 0; kd < 1056; ++kd)
    acc = fmaf(sp[kd], Vr[kd*32 + f], acc);
  float deg = (float)max(counts[n], 1);
  float rt = 0.f;
  #pragma unroll
  for (int k=0;k<32;++k) rt = fmaf(cur[n*32+k], root_w[k*32+f], rt);
  float val = acc/deg + rt + conv_b[f];
  m[n*32+f] = fmaxf(val, 0.f);
}

__global__ __launch_bounds__(256) void k_gru(
    const float* __restrict__ m, float* __restrict__ h,
    const float* __restrict__ wih, const float* __restrict__ whh,
    const float* __restrict__ bih, const float* __restrict__ bhh, int N){
  __shared__ float wl[2*3072];
  __shared__ float mh[8][64];
  int t = threadIdx.x;
  for (int i = t; i < 3072; i += 256){ wl[i] = wih[i]; wl[3072+i] = whh[i]; }
  int nb = blockIdx.x*8;
  for (int i = t; i < 8*64; i += 256){
    int node = nb + (i>>6); int c = i & 63;
    if (node < N) mh[i>>6][c] = (c < 32) ? m[node*32+c] : h[node*32 + (c-32)];
  }
  __syncthreads();
  int sub = t >> 5, d = t & 31, n = nb + sub;
  if (n >= N) return;
  float gr = bih[d], gz = bih[32+d], gn = bih[64+d];
  float hr = bhh[d], hz = bhh[32+d], hn = bhh[64+d];
  const float* mm = mh[sub];
  const float* hh = mh[sub] + 32;
  #pragma unroll
  for (int k=0;k<32;++k){
    float mv = mm[k], hv = hh[k];
    gr = fmaf(mv, wl[k*96 + d],      gr);
    gz = fmaf(mv, wl[k*96 + 32 + d], gz);
    gn = fmaf(mv, wl[k*96 + 64 + d], gn);
    hr = fmaf(hv, wl[3072 + k*96 + d],      hr);
    hz = fmaf(hv, wl[3072 + k*96 + 32 + d], hz);
    hn = fmaf(hv, wl[3072 + k*96 + 64 + d], hn);
  }
  float r = sigf(gr + hr);
  float z = sigf(gz + hz);
  float nn = tanhf(gn + r*hn);
  h[n*32+d] = (1.f - z)*nn + z*hh[d];
}

// whole Set2Set (6 iters) + memory LSTM + FC head; one block per graph
__global__ __launch_bounds__(512) void k_s2s(
    const float* __restrict__ cur,
    const float* __restrict__ wi, const float* __restrict__ wh, const float* __restrict__ sb,
    const float* __restrict__ mwi, const float* __restrict__ mwh, const float* __restrict__ mb,
    const float* __restrict__ hx, const float* __restrict__ cx,
    const float* __restrict__ f1w, const float* __restrict__ f1b,
    const float* __restrict__ f2w, const float* __restrict__ f2b,
    float* __restrict__ out, int N, int G){
  int g = blockIdx.x, t = threadIdx.x;
  int lo = (int)(((long long)g*N + G - 1)/G);
  int hi = (int)(((long long)(g+1)*N + G - 1)/G);
  int cnt = hi - lo;
  __shared__ float qstar[64], hsS[32], csS[32], gbuf[128];
  __shared__ float ebuf[512];
  __shared__ float redr[8*32];
  __shared__ float smax[8], ssum[8];
  __shared__ float bmaxS, bsumS;
  __shared__ float hnew[32], f1o[32];
  if (t < 64) qstar[t] = 0.f;
  if (t < 32){ hsS[t] = 0.f; csS[t] = 0.f; }
  __syncthreads();
  int wv = t >> 6, l = t & 63, d = l & 31, halfw = l >> 5;
  for (int it = 0; it < 6; ++it){
    if (t < 128){
      float acc = sb[t];
      for (int j=0;j<64;++j) acc = fmaf(qstar[j], wi[j*128+t], acc);
      for (int j=0;j<32;++j) acc = fmaf(hsS[j],  wh[j*128+t], acc);
      gbuf[t] = acc;
    }
    __syncthreads();
    if (t < 32){
      float c = sigf(gbuf[32+t])*csS[t] + sigf(gbuf[t])*tanhf(gbuf[64+t]);
      csS[t] = c;
      hsS[t] = sigf(gbuf[96+t])*tanhf(c);
    }
    __syncthreads();
    // pass 1: e_n = <cur[n], q>, block max
    float lmax = -1e30f;
    for (int p = wv*2 + halfw; p < cnt; p += 16){
      float prod = cur[(lo + p)*32 + d] * hsS[d];
      for (int o2 = 1; o2 < 32; o2 <<= 1) prod += __shfl_xor(prod, o2, 64);
      if (d == 0) ebuf[p] = prod;
      lmax = fmaxf(lmax, prod);
    }
    for (int o2 = 1; o2 < 64; o2 <<= 1) lmax = fmaxf(lmax, __shfl_xor(lmax, o2, 64));
    if (l == 0) smax[wv] = lmax;
    __syncthreads();
    if (t == 0){ float mm = smax[0]; for (int i=1;i<8;++i) mm = fmaxf(mm, smax[i]); bmaxS = mm; }
    __syncthreads();
    float bmax = bmaxS;
    // pass 2: a=exp(e-max); accumulate sum(a) and sum(a*cur)
    float asum = 0.f, racc = 0.f;
    for (int p = wv*2 + halfw; p < cnt; p += 16){
      float a = expf(ebuf[p] - bmax);
      if (d == 0) asum += a;
      racc = fmaf(a, cur[(lo + p)*32 + d], racc);
    }
    racc += __shfl_xor(racc, 32, 64);
    for (int o2 = 1; o2 < 64; o2 <<= 1) asum += __shfl_xor(asum, o2, 64);
    if (l < 32) redr[wv*32 + l] = racc;
    if (l == 0) ssum[wv] = asum;
    __syncthreads();
    if (t == 0){ float s2 = 0.f; for (int i=0;i<8;++i) s2 += ssum[i]; bsumS = s2; }
    __syncthreads();
    if (t < 32){
      float rsum = 0.f;
      for (int w2=0; w2<8; ++w2) rsum += redr[w2*32 + t];
      qstar[32 + t] = rsum / bsumS;
      qstar[t] = hsS[t];
    }
    __syncthreads();
  }
  // memory LSTM + FC head
  if (t < 128){
    float acc = mb[t];
    for (int j=0;j<64;++j) acc = fmaf(qstar[j], mwi[j*128+t], acc);
    for (int j=0;j<32;++j) acc = fmaf(hx[g*32+j], mwh[j*128+t], acc);
    gbuf[t] = acc;
  }
  __syncthreads();
  if (t < 32){
    float c = sigf(gbuf[32+t])*cx[g*32+t] + sigf(gbuf[t])*tanhf(gbuf[64+t]);
    float h = sigf(gbuf[96+t])*tanhf(c);
    out[G + g*32 + t] = h;            // h_new
    out[G + G*32 + g*32 + t] = c;     // c_new
    hnew[t] = h;
  }
  __syncthreads();
  if (t < 32){
    float acc = f1b[t];
    #pragma unroll
    for (int k=0;k<32;++k) acc = fmaf(hnew[k], f1w[k*32+t], acc);
    f1o[t] = fmaxf(acc, 0.f);
  }
  __syncthreads();
  if (t == 0){
    float acc = f2b[0];
    #pragma unroll
    for (int k=0;k<32;++k) acc = fmaf(f1o[k], f2w[k], acc);
    out[g] = acc;                     // v
  }
}

extern "C" void kernel_launch(void* const* d_in, const int* in_sizes, int n_in,
                              void* d_out, int out_size, void* d_ws, size_t ws_size,
                              hipStream_t stream) {
  const float* x      = (const float*)d_in[0];
  const float* ea     = (const float*)d_in[1];
  const float* hx     = (const float*)d_in[2];
  const float* cx     = (const float*)d_in[3];
  const float* lin0_w = (const float*)d_in[4];
  const float* lin0_b = (const float*)d_in[5];
  const float* e_w1   = (const float*)d_in[6];
  const float* e_b1   = (const float*)d_in[7];
  const float* e_w2   = (const float*)d_in[8];
  const float* e_b2   = (const float*)d_in[9];
  const float* root_w = (const float*)d_in[10];
  const float* conv_b = (const float*)d_in[11];
  const float* g_wih  = (const float*)d_in[12];
  const float* g_whh  = (const float*)d_in[13];
  const float* g_bih  = (const float*)d_in[14];
  const float* g_bhh  = (const float*)d_in[15];
  const float* s_wi   = (const float*)d_in[16];
  const float* s_wh   = (const float*)d_in[17];
  const float* s_b    = (const float*)d_in[18];
  const float* m_wi   = (const float*)d_in[19];
  const float* m_wh   = (const float*)d_in[20];
  const float* m_b    = (const float*)d_in[21];
  const float* f1w    = (const float*)d_in[22];
  const float* f1b    = (const float*)d_in[23];
  const float* f2w    = (const float*)d_in[24];
  const float* f2b    = (const float*)d_in[25];
  const int*   eidx   = (const int*)d_in[26];
  int N = in_sizes[0]/3;
  int E = in_sizes[1]/4;
  int G = in_sizes[2]/32;
  const int* srcI = eidx;
  const int* dstI = eidx + E;
  float* outF = (float*)d_out;

  // workspace carve (~84 MB)
  char* wbase = (char*)d_ws; size_t off = 0;
  auto carve = [&](size_t nbytes)->char*{
    char* p = wbase + off; off = (off + nbytes + 255) & ~(size_t)255; return p;
  };
  float* cur     = (float*)carve((size_t)N*32*4);
  float* hid     = (float*)carve((size_t)E*32*4);
  float* S       = (float*)carve((size_t)N*1056*4);
  float* mbuf    = (float*)carve((size_t)N*32*4);
  float* Vr      = (float*)carve((size_t)1056*32*4);
  int*   counts  = (int*)carve((size_t)N*4);
  int*   cursor  = (int*)carve((size_t)N*4);
  int*   row_off = (int*)carve((size_t)(N+1)*4);
  int*   eid     = (int*)carve((size_t)E*4);
  (void)ws_size; (void)n_in; (void)out_size;

  // phase A: node/edge embeddings + dst-CSR + permuted W2
  k_init<<<(N+255)/256, 256, 0, stream>>>(counts, cursor, N);
  k_lin0<<<(N*32+255)/256, 256, 0, stream>>>(x, lin0_w, lin0_b, cur, N);
  k_hidden<<<(E*32+255)/256, 256, 0, stream>>>(ea, e_w1, e_b1, hid, E);
  k_count<<<(E+255)/256, 256, 0, stream>>>(dstI, counts, E);
  k_scan<<<1, 256, 0, stream>>>(counts, row_off, N);
  k_scatter<<<(E+255)/256, 256, 0, stream>>>(dstI, row_off, cursor, eid, E);
  k_permW2<<<(1056*32+255)/256, 256, 0, stream>>>(e_w2, e_b2, Vr);

  // phase B: 6 message-passing + GRU iterations
  for (int it = 0; it < 6; ++it){
    k_S<<<(N+3)/4, 256, 0, stream>>>(row_off, eid, srcI, hid, cur, S, N);
    k_aggr_m<<<(N+7)/8, 256, 0, stream>>>(S, Vr, cur, root_w, conv_b, counts, mbuf, N);
    k_gru<<<(N+7)/8, 256, 0, stream>>>(mbuf, cur, g_wih, g_whh, g_bih, g_bhh, N);
  }

  // phase C+D: Set2Set x6 + memory LSTM + FC head (one kernel)
  k_s2s<<<G, 512, 0, stream>>>(cur, s_wi, s_wh, s_b, m_wi, m_wh, m_b,
                               hx, cx, f1w, f1b, f2w, f2b, outF, N, G);
}

// Round 2
// 1005.368 us; speedup vs baseline: 1.0546x; 1.0546x over previous
//
#include <hip/hip_runtime.h>
#include <math.h>

// CriticBatchNet: NNConv(+edge-net) + GRU x6, Set2Set x6, LSTM head.
// msg[e] = out[src]@W_e[e], W_e[e]=hidden[e]@e_w2+b2
//   => segsum_dst(msg)[m,f] = sum_kd S[m,kd]*Vr[kd,f],
//      S[m,k*32+d] = sum_{e:dst=m} hidden[e,k]*out[src_e,d]
//      S[m,1024+j] = sum_{e:dst=m} out[src_e,j]   (bias rows)
// v2: S lives only in LDS (fused iter kernel, ping-pong cur buffers);
//     hid/src pre-permuted to CSR order; k_s2s caches cur in registers.

__device__ __forceinline__ float sigf(float x){ return 1.f/(1.f+expf(-x)); }

__global__ void k_init(int* __restrict__ counts, int* __restrict__ cursor, int N){
  int i = blockIdx.x*blockDim.x + threadIdx.x;
  if (i < N){ counts[i]=0; cursor[i]=0; }
}

__global__ void k_lin0(const float* __restrict__ x, const float* __restrict__ w,
                       const float* __restrict__ b, float* __restrict__ cur, int N){
  int i = blockIdx.x*blockDim.x + threadIdx.x;
  if (i >= N*32) return;
  int n = i>>5, d = i&31;
  float acc = b[d];
  acc = fmaf(x[n*3+0], w[0*32+d], acc);
  acc = fmaf(x[n*3+1], w[1*32+d], acc);
  acc = fmaf(x[n*3+2], w[2*32+d], acc);
  cur[i] = fmaxf(acc, 0.f);
}

__global__ void k_hidden(const float* __restrict__ ea, const float* __restrict__ w,
                         const float* __restrict__ b, float* __restrict__ hid, int E){
  int i = blockIdx.x*blockDim.x + threadIdx.x;
  if (i >= E*32) return;
  int e = i>>5, k = i&31;
  float acc = b[k];
  #pragma unroll
  for (int j=0;j<4;++j) acc = fmaf(ea[e*4+j], w[j*32+k], acc);
  hid[i] = fmaxf(acc, 0.f);
}

__global__ void k_count(const int* __restrict__ dst, int* __restrict__ counts, int E){
  int i = blockIdx.x*blockDim.x + threadIdx.x;
  if (i < E) atomicAdd(&counts[dst[i]], 1);
}

__global__ void k_scan(const int* __restrict__ counts, int* __restrict__ row_off, int N){
  __shared__ int buf[256];
  __shared__ int carry;
  int t = threadIdx.x;
  if (t == 0) carry = 0;
  __syncthreads();
  for (int base = 0; base < N; base += 256){
    int v = (base + t < N) ? counts[base + t] : 0;
    buf[t] = v; __syncthreads();
    for (int off = 1; off < 256; off <<= 1){
      int tmp = (t >= off) ? buf[t-off] : 0;
      __syncthreads();
      buf[t] += tmp;
      __syncthreads();
    }
    if (base + t < N) row_off[base + t] = carry + buf[t] - v;
    __syncthreads();
    if (t == 255) carry += buf[255];
    __syncthreads();
  }
  if (t == 0) row_off[N] = carry;
}

__global__ void k_scatter(const int* __restrict__ dst, const int* __restrict__ row_off,
                          int* __restrict__ cursor, int* __restrict__ eid, int E){
  int i = blockIdx.x*blockDim.x + threadIdx.x;
  if (i < E){
    int dn = dst[i];
    int pos = row_off[dn] + atomicAdd(&cursor[dn], 1);
    eid[pos] = i;
  }
}

__global__ void k_permW2(const float* __restrict__ e_w2, const float* __restrict__ e_b2,
                         float* __restrict__ Vr){
  int idx = blockIdx.x*blockDim.x + threadIdx.x;
  if (idx >= 1056*32) return;
  int f = idx & 31, kd = idx >> 5;
  Vr[idx] = (kd < 1024) ? e_w2[(kd>>5)*1024 + (kd&31)*32 + f]
                        : e_b2[(kd-1024)*32 + f];
}

// hidp[p] = hid[eid[p]], srcp[p] = src[eid[p]] : CSR-ordered edge data
__global__ void k_permEdge(const int* __restrict__ eid, const int* __restrict__ src,
                           const float* __restrict__ hid, float* __restrict__ hidp,
                           int* __restrict__ srcp, int E){
  int i = blockIdx.x*blockDim.x + threadIdx.x;
  if (i >= E*32) return;
  int p = i>>5, d = i&31;
  int e = eid[p];
  hidp[i] = hid[e*32 + d];
  if (d == 0) srcp[p] = src[e];
}

// Fused per-iteration kernel: S (LDS) -> contraction -> root/relu -> GRU.
// 8 nodes per block of 256 threads; reads cur_in, writes cur_out.
__global__ __launch_bounds__(256) void k_iter(
    const int* __restrict__ row_off, const int* __restrict__ srcp,
    const float* __restrict__ hidp, const float* __restrict__ cur_in,
    const float* __restrict__ Vr, const float* __restrict__ root_w,
    const float* __restrict__ conv_b,
    const float* __restrict__ wih, const float* __restrict__ whh,
    const float* __restrict__ bih, const float* __restrict__ bhh,
    float* __restrict__ cur_out, int N){
  __shared__ float s_lds[8*1056];
  __shared__ float mtile[256];
  __shared__ float htile[256];
  int nb = blockIdx.x*8;
  int t = threadIdx.x;
  int w = t >> 6, l = t & 63, d = l & 31, hiL = l >> 5;

  // phase 1: per-wave, 2 nodes sequentially; S row accumulated in regs
  #pragma unroll
  for (int q = 0; q < 2; ++q){
    int n = nb + 2*w + q;
    float acc[16];
    #pragma unroll
    for (int r=0;r<16;++r) acc[r]=0.f;
    float aex = 0.f;
    if (n < N){
      int lo = row_off[n], hi = row_off[n+1];
      for (int p = lo; p < hi; ++p){
        float h_own = hidp[p*32 + d];
        int s = srcp[p];
        float o_own = cur_in[s*32 + d];
        #pragma unroll
        for (int r=0;r<16;++r){
          float hk = __shfl(h_own, 2*r + hiL, 64);
          acc[r] = fmaf(hk, o_own, acc[r]);
        }
        aex += o_own;
      }
    }
    float* sp = &s_lds[(2*w+q)*1056];
    #pragma unroll
    for (int r=0;r<16;++r) sp[r*64 + l] = acc[r];
    if (l < 32) sp[1024 + l] = aex;
  }
  __syncthreads();

  // phase 2: contraction + root + relu -> m
  int sub = t >> 5, f = t & 31;
  int n = nb + sub;
  {
    const float* sp = &s_lds[sub*1056];
    float acc = 0.f;
    #pragma unroll 8
    for (int kd = 0; kd < 1056; ++kd)
      acc = fmaf(sp[kd], Vr[kd*32 + f], acc);
    if (n < N){
      float deg = (float)max(row_off[n+1] - row_off[n], 1);
      float rt = 0.f;
      #pragma unroll
      for (int k=0;k<32;++k) rt = fmaf(cur_in[n*32+k], root_w[k*32+f], rt);
      float mval = fmaxf(acc/deg + rt + conv_b[f], 0.f);
      mtile[sub*32 + f] = mval;
      htile[sub*32 + f] = cur_in[n*32 + f];
    }
  }
  __syncthreads();

  // phase 3: GRU
  if (n < N){
    float gr = bih[f], gz = bih[32+f], gn = bih[64+f];
    float hr = bhh[f], hz = bhh[32+f], hn = bhh[64+f];
    const float* mm = &mtile[sub*32];
    const float* hh = &htile[sub*32];
    #pragma unroll
    for (int k=0;k<32;++k){
      float mv = mm[k], hv = hh[k];
      gr = fmaf(mv, wih[k*96 + f],      gr);
      gz = fmaf(mv, wih[k*96 + 32 + f], gz);
      gn = fmaf(mv, wih[k*96 + 64 + f], gn);
      hr = fmaf(hv, whh[k*96 + f],      hr);
      hz = fmaf(hv, whh[k*96 + 32 + f], hz);
      hn = fmaf(hv, whh[k*96 + 64 + f], hn);
    }
    float r = sigf(gr + hr);
    float z = sigf(gz + hz);
    float nn2 = tanhf(gn + r*hn);
    cur_out[n*32 + f] = (1.f - z)*nn2 + z*hh[f];
  }
}

// Set2Set x6 + memory LSTM + FC head; one block per graph; cur cached in regs.
__global__ __launch_bounds__(512) void k_s2s(
    const float* __restrict__ cur,
    const float* __restrict__ wi, const float* __restrict__ wh, const float* __restrict__ sb,
    const float* __restrict__ mwi, const float* __restrict__ mwh, const float* __restrict__ mb,
    const float* __restrict__ hx, const float* __restrict__ cx,
    const float* __restrict__ f1w, const float* __restrict__ f1b,
    const float* __restrict__ f2w, const float* __restrict__ f2b,
    float* __restrict__ out, int N, int G){
  int g = blockIdx.x, t = threadIdx.x;
  int lo = (int)(((long long)g*N + G - 1)/G);
  int hi = (int)(((long long)(g+1)*N + G - 1)/G);
  int cnt = hi - lo;
  __shared__ float qstar[64], hsS[32], csS[32], gbuf[128];
  __shared__ float ebuf[1024];
  __shared__ float redr[8*32];
  __shared__ float smax[8], ssum[8];
  __shared__ float bmaxS, bsumS;
  __shared__ float hnew[32], f1o[32];
  if (t < 64) qstar[t] = 0.f;
  if (t < 32){ hsS[t] = 0.f; csS[t] = 0.f; }
  __syncthreads();
  int wv = t >> 6, l = t & 63, d = l & 31, halfw = l >> 5;
  int p0 = wv*2 + halfw;
  // register-cache this lane's cur values (fixed across all iterations)
  float cv[32];
  #pragma unroll
  for (int i=0;i<32;++i){
    int p = p0 + 16*i;
    cv[i] = (p < cnt) ? cur[(lo + p)*32 + d] : 0.f;
  }
  for (int it = 0; it < 6; ++it){
    if (t < 128){
      float acc = sb[t];
      for (int j=0;j<64;++j) acc = fmaf(qstar[j], wi[j*128+t], acc);
      for (int j=0;j<32;++j) acc = fmaf(hsS[j],  wh[j*128+t], acc);
      gbuf[t] = acc;
    }
    __syncthreads();
    if (t < 32){
      float c = sigf(gbuf[32+t])*csS[t] + sigf(gbuf[t])*tanhf(gbuf[64+t]);
      csS[t] = c;
      hsS[t] = sigf(gbuf[96+t])*tanhf(c);
    }
    __syncthreads();
    // pass 1: e = <cur[n], q>, block max
    float lmax = -1e30f;
    float qd = hsS[d];
    #pragma unroll
    for (int i=0;i<32;++i){
      int p = p0 + 16*i;
      float prod = cv[i]*qd;
      #pragma unroll
      for (int o2 = 1; o2 < 32; o2 <<= 1) prod += __shfl_xor(prod, o2, 64);
      if (p < cnt){
        if (d == 0) ebuf[p] = prod;
        lmax = fmaxf(lmax, prod);
      }
    }
    for (int p = p0 + 512; p < cnt; p += 16){ // generic fallback (unused at N=15000,G=32)
      float prod = cur[(lo+p)*32+d]*qd;
      for (int o2 = 1; o2 < 32; o2 <<= 1) prod += __shfl_xor(prod, o2, 64);
      if (d == 0) ebuf[p] = prod;
      lmax = fmaxf(lmax, prod);
    }
    #pragma unroll
    for (int o2 = 1; o2 < 64; o2 <<= 1) lmax = fmaxf(lmax, __shfl_xor(lmax, o2, 64));
    if (l == 0) smax[wv] = lmax;
    __syncthreads();
    if (t == 0){ float mm = smax[0]; for (int i=1;i<8;++i) mm = fmaxf(mm, smax[i]); bmaxS = mm; }
    __syncthreads();
    float bmax = bmaxS;
    // pass 2: a=exp(e-max); sum(a), sum(a*cur)
    float asum = 0.f, racc = 0.f;
    #pragma unroll
    for (int i=0;i<32;++i){
      int p = p0 + 16*i;
      if (p < cnt){
        float a = expf(ebuf[p] - bmax);
        if (d == 0) asum += a;
        racc = fmaf(a, cv[i], racc);
      }
    }
    for (int p = p0 + 512; p < cnt; p += 16){
      float a = expf(ebuf[p] - bmax);
      if (d == 0) asum += a;
      racc = fmaf(a, cur[(lo+p)*32+d], racc);
    }
    racc += __shfl_xor(racc, 32, 64);
    #pragma unroll
    for (int o2 = 1; o2 < 64; o2 <<= 1) asum += __shfl_xor(asum, o2, 64);
    if (l < 32) redr[wv*32 + l] = racc;
    if (l == 0) ssum[wv] = asum;
    __syncthreads();
    if (t == 0){ float s2 = 0.f; for (int i=0;i<8;++i) s2 += ssum[i]; bsumS = s2; }
    __syncthreads();
    if (t < 32){
      float rsum = 0.f;
      for (int w2=0; w2<8; ++w2) rsum += redr[w2*32 + t];
      qstar[32 + t] = rsum / bsumS;
      qstar[t] = hsS[t];
    }
    __syncthreads();
  }
  // memory LSTM + FC head
  if (t < 128){
    float acc = mb[t];
    for (int j=0;j<64;++j) acc = fmaf(qstar[j], mwi[j*128+t], acc);
    for (int j=0;j<32;++j) acc = fmaf(hx[g*32+j], mwh[j*128+t], acc);
    gbuf[t] = acc;
  }
  __syncthreads();
  if (t < 32){
    float c = sigf(gbuf[32+t])*cx[g*32+t] + sigf(gbuf[t])*tanhf(gbuf[64+t]);
    float h = sigf(gbuf[96+t])*tanhf(c);
    out[G + g*32 + t] = h;
    out[G + G*32 + g*32 + t] = c;
    hnew[t] = h;
  }
  __syncthreads();
  if (t < 32){
    float acc = f1b[t];
    #pragma unroll
    for (int k=0;k<32;++k) acc = fmaf(hnew[k], f1w[k*32+t], acc);
    f1o[t] = fmaxf(acc, 0.f);
  }
  __syncthreads();
  if (t == 0){
    float acc = f2b[0];
    #pragma unroll
    for (int k=0;k<32;++k) acc = fmaf(f1o[k], f2w[k], acc);
    out[g] = acc;
  }
}

extern "C" void kernel_launch(void* const* d_in, const int* in_sizes, int n_in,
                              void* d_out, int out_size, void* d_ws, size_t ws_size,
                              hipStream_t stream) {
  const float* x      = (const float*)d_in[0];
  const float* ea     = (const float*)d_in[1];
  const float* hx     = (const float*)d_in[2];
  const float* cx     = (const float*)d_in[3];
  const float* lin0_w = (const float*)d_in[4];
  const float* lin0_b = (const float*)d_in[5];
  const float* e_w1   = (const float*)d_in[6];
  const float* e_b1   = (const float*)d_in[7];
  const float* e_w2   = (const float*)d_in[8];
  const float* e_b2   = (const float*)d_in[9];
  const float* root_w = (const float*)d_in[10];
  const float* conv_b = (const float*)d_in[11];
  const float* g_wih  = (const float*)d_in[12];
  const float* g_whh  = (const float*)d_in[13];
  const float* g_bih  = (const float*)d_in[14];
  const float* g_bhh  = (const float*)d_in[15];
  const float* s_wi   = (const float*)d_in[16];
  const float* s_wh   = (const float*)d_in[17];
  const float* s_b    = (const float*)d_in[18];
  const float* m_wi   = (const float*)d_in[19];
  const float* m_wh   = (const float*)d_in[20];
  const float* m_b    = (const float*)d_in[21];
  const float* f1w    = (const float*)d_in[22];
  const float* f1b    = (const float*)d_in[23];
  const float* f2w    = (const float*)d_in[24];
  const float* f2b    = (const float*)d_in[25];
  const int*   eidx   = (const int*)d_in[26];
  int N = in_sizes[0]/3;
  int E = in_sizes[1]/4;
  int G = in_sizes[2]/32;
  const int* srcI = eidx;
  const int* dstI = eidx + E;
  float* outF = (float*)d_out;

  char* wbase = (char*)d_ws; size_t off = 0;
  auto carve = [&](size_t nbytes)->char*{
    char* p = wbase + off; off = (off + nbytes + 255) & ~(size_t)255; return p;
  };
  float* cur0    = (float*)carve((size_t)N*32*4);
  float* cur1    = (float*)carve((size_t)N*32*4);
  float* hid     = (float*)carve((size_t)E*32*4);
  float* hidp    = (float*)carve((size_t)E*32*4);
  float* Vr      = (float*)carve((size_t)1056*32*4);
  int*   counts  = (int*)carve((size_t)N*4);
  int*   cursor  = (int*)carve((size_t)N*4);
  int*   row_off = (int*)carve((size_t)(N+1)*4);
  int*   eid     = (int*)carve((size_t)E*4);
  int*   srcp    = (int*)carve((size_t)E*4);
  (void)ws_size; (void)n_in; (void)out_size;

  // phase A: embeddings + dst-CSR + permuted W2 + CSR-ordered edge data
  k_init<<<(N+255)/256, 256, 0, stream>>>(counts, cursor, N);
  k_lin0<<<(N*32+255)/256, 256, 0, stream>>>(x, lin0_w, lin0_b, cur0, N);
  k_hidden<<<(E*32+255)/256, 256, 0, stream>>>(ea, e_w1, e_b1, hid, E);
  k_count<<<(E+255)/256, 256, 0, stream>>>(dstI, counts, E);
  k_scan<<<1, 256, 0, stream>>>(counts, row_off, N);
  k_scatter<<<(E+255)/256, 256, 0, stream>>>(dstI, row_off, cursor, eid, E);
  k_permW2<<<(1056*32+255)/256, 256, 0, stream>>>(e_w2, e_b2, Vr);
  k_permEdge<<<(E*32+255)/256, 256, 0, stream>>>(eid, srcI, hid, hidp, srcp, E);

  // phase B: 6 fused message-passing + GRU iterations (ping-pong cur)
  float* cin = cur0; float* cout = cur1;
  for (int it = 0; it < 6; ++it){
    k_iter<<<(N+7)/8, 256, 0, stream>>>(row_off, srcp, hidp, cin, Vr, root_w,
                                        conv_b, g_wih, g_whh, g_bih, g_bhh, cout, N);
    float* tmp = cin; cin = cout; cout = tmp;
  }

  // phase C+D: Set2Set x6 + memory LSTM + FC head (reads cur0 after 6 iters)
  k_s2s<<<G, 512, 0, stream>>>(cin, s_wi, s_wh, s_b, m_wi, m_wh, m_b,
                               hx, cx, f1w, f1b, f2w, f2b, outF, N, G);
}

// Round 3
// 787.577 us; speedup vs baseline: 1.3463x; 1.2765x over previous
//
#include <hip/hip_runtime.h>
#include <math.h>

// CriticBatchNet: NNConv(+edge-net) + GRU x6, Set2Set x6, LSTM head.
// msg[e] = out[src]@W_e[e], W_e[e]=hidden[e]@e_w2+b2
//   => segsum_dst(msg)[m,f] = sum_kd S[m,kd]*Vr[kd,f],
//      S[m,k*32+d] = sum_{e:dst=m} hidden[e,k]*out[src_e,d]
//      S[m,1024+j] = sum_{e:dst=m} out[src_e,j]   (bias rows)
// v3: phase-2 contraction via MFMA bf16x3 (split-precision), K-split across
//     8 waves; phase-1 1 node/wave + depth-2 prefetch; hidden fused into CSR
//     permute. S lives only in LDS.

typedef __attribute__((ext_vector_type(8))) short short8;
typedef __attribute__((ext_vector_type(4))) float f32x4;

__device__ __forceinline__ float sigf(float x){ return 1.f/(1.f+expf(-x)); }

__global__ void k_init(int* __restrict__ counts, int* __restrict__ cursor, int N){
  int i = blockIdx.x*blockDim.x + threadIdx.x;
  if (i < N){ counts[i]=0; cursor[i]=0; }
}

__global__ void k_lin0(const float* __restrict__ x, const float* __restrict__ w,
                       const float* __restrict__ b, float* __restrict__ cur, int N){
  int i = blockIdx.x*blockDim.x + threadIdx.x;
  if (i >= N*32) return;
  int n = i>>5, d = i&31;
  float acc = b[d];
  acc = fmaf(x[n*3+0], w[0*32+d], acc);
  acc = fmaf(x[n*3+1], w[1*32+d], acc);
  acc = fmaf(x[n*3+2], w[2*32+d], acc);
  cur[i] = fmaxf(acc, 0.f);
}

__global__ void k_count(const int* __restrict__ dst, int* __restrict__ counts, int E){
  int i = blockIdx.x*blockDim.x + threadIdx.x;
  if (i < E) atomicAdd(&counts[dst[i]], 1);
}

__global__ void k_scan(const int* __restrict__ counts, int* __restrict__ row_off, int N){
  __shared__ int buf[256];
  __shared__ int carry;
  int t = threadIdx.x;
  if (t == 0) carry = 0;
  __syncthreads();
  for (int base = 0; base < N; base += 256){
    int v = (base + t < N) ? counts[base + t] : 0;
    buf[t] = v; __syncthreads();
    for (int off = 1; off < 256; off <<= 1){
      int tmp = (t >= off) ? buf[t-off] : 0;
      __syncthreads();
      buf[t] += tmp;
      __syncthreads();
    }
    if (base + t < N) row_off[base + t] = carry + buf[t] - v;
    __syncthreads();
    if (t == 255) carry += buf[255];
    __syncthreads();
  }
  if (t == 0) row_off[N] = carry;
}

__global__ void k_scatter(const int* __restrict__ dst, const int* __restrict__ row_off,
                          int* __restrict__ cursor, int* __restrict__ eid, int E){
  int i = blockIdx.x*blockDim.x + threadIdx.x;
  if (i < E){
    int dn = dst[i];
    int pos = row_off[dn] + atomicAdd(&cursor[dn], 1);
    eid[pos] = i;
  }
}

// fused: hidp[p] = relu(ea[eid[p]] @ e_w1 + e_b1), srcp[p] = src[eid[p]]
__global__ void k_edgeCSR(const int* __restrict__ eid, const int* __restrict__ src,
                          const float* __restrict__ ea, const float* __restrict__ w,
                          const float* __restrict__ b, float* __restrict__ hidp,
                          int* __restrict__ srcp, int E){
  int i = blockIdx.x*blockDim.x + threadIdx.x;
  if (i >= E*32) return;
  int p = i>>5, d = i&31;
  int e = eid[p];
  const float4* ea4 = (const float4*)ea;
  float4 v = ea4[e];
  float acc = b[d];
  acc = fmaf(v.x, w[0*32+d], acc);
  acc = fmaf(v.y, w[1*32+d], acc);
  acc = fmaf(v.z, w[2*32+d], acc);
  acc = fmaf(v.w, w[3*32+d], acc);
  hidp[i] = fmaxf(acc, 0.f);
  if (d == 0) srcp[p] = src[e];
}

// VrT_hi/lo[f*1056 + kd] : transposed + truncation-split bf16 of
//   Vr[kd,f] = (kd<1024) ? e_w2[(kd>>5)*1024 + (kd&31)*32 + f] : e_b2[(kd-1024)*32+f]
__global__ void k_permW2split(const float* __restrict__ e_w2, const float* __restrict__ e_b2,
                              unsigned short* __restrict__ VrT_hi,
                              unsigned short* __restrict__ VrT_lo){
  int idx = blockIdx.x*blockDim.x + threadIdx.x;
  if (idx >= 1056*32) return;
  int f = idx & 31, kd = idx >> 5;
  float v = (kd < 1024) ? e_w2[(kd>>5)*1024 + (kd&31)*32 + f]
                        : e_b2[(kd-1024)*32 + f];
  unsigned ub = __float_as_uint(v);
  unsigned hb = ub & 0xFFFF0000u;
  float res = v - __uint_as_float(hb);
  VrT_hi[f*1056 + kd] = (unsigned short)(ub >> 16);
  VrT_lo[f*1056 + kd] = (unsigned short)(__float_as_uint(res) >> 16);
}

// Fused per-iteration kernel: S build (LDS) -> MFMA contraction (bf16x3)
//   -> root/relu -> GRU. 8 nodes per 512-thread block (8 waves).
__global__ __launch_bounds__(512) void k_iter(
    const int* __restrict__ row_off, const int* __restrict__ srcp,
    const float* __restrict__ hidp, const float* __restrict__ cur_in,
    const unsigned short* __restrict__ VrT_hi, const unsigned short* __restrict__ VrT_lo,
    const float* __restrict__ root_w, const float* __restrict__ conv_b,
    const float* __restrict__ wih, const float* __restrict__ whh,
    const float* __restrict__ bih, const float* __restrict__ bhh,
    float* __restrict__ cur_out, int N){
  __shared__ __align__(16) float s_lds[8*1056];   // S rows [node][kd]
  __shared__ float pbuf[8][8][32];                // per-wave partial aggr
  __shared__ float mtile[8*32];
  __shared__ float htile[8*32];
  int nb = blockIdx.x*8;
  int t = threadIdx.x;
  int w = t >> 6, l = t & 63, d = l & 31, hiL = l >> 5;

  // ---- phase 1: node n = nb + w; outer-product accumulate S in regs ----
  int n = nb + w;
  float acc[16];
  #pragma unroll
  for (int r=0;r<16;++r) acc[r]=0.f;
  float aex = 0.f;
  if (n < N){
    int lo = row_off[n], hi = row_off[n+1];
    int p = lo;
    float h0=0.f, o0=0.f, h1=0.f, o1=0.f;
    if (p < hi){ h0 = hidp[p*32+d]; int s0 = srcp[p]; o0 = cur_in[s0*32+d]; }
    if (p+1 < hi){ h1 = hidp[(p+1)*32+d]; int s1 = srcp[p+1]; o1 = cur_in[s1*32+d]; }
    for (; p < hi; ++p){
      float hc = h0, oc = o0;
      h0 = h1; o0 = o1;
      if (p+2 < hi){ h1 = hidp[(p+2)*32+d]; int s2 = srcp[p+2]; o1 = cur_in[s2*32+d]; }
      #pragma unroll
      for (int r=0;r<16;++r){
        float hk = __shfl(hc, 2*r + hiL, 64);
        acc[r] = fmaf(hk, oc, acc[r]);
      }
      aex += oc;
    }
  }
  {
    float* sp = &s_lds[w*1056];
    #pragma unroll
    for (int r=0;r<16;++r) sp[r*64 + l] = acc[r];
    if (l < 32) sp[1024 + l] = aex;
  }
  __syncthreads();

  // ---- phase 2: MFMA contraction, K split across 8 waves ----
  // C[m][f] = sum_kd S[m][kd] * Vr[kd][f];  M=16 tile (rows 8..15 zero)
  {
    int fc = l & 15;          // A-row (node) on input side; C-col on output side
    int hq = l >> 4;          // 0..3  (k sub-block)
    bool aok = fc < 8;
    const float* arow = &s_lds[(fc & 7)*1056];
    const unsigned short* bh0p = VrT_hi + fc*1056;
    const unsigned short* bl0p = VrT_lo + fc*1056;
    const unsigned short* bh1p = VrT_hi + (16+fc)*1056;
    const unsigned short* bl1p = VrT_lo + (16+fc)*1056;
    f32x4 acc0 = {0.f,0.f,0.f,0.f}, acc1 = {0.f,0.f,0.f,0.f};
    int s_lo = w*4, s_hi = (w == 7) ? 33 : w*4 + 4;   // 33 K-steps of 32
    for (int st = s_lo; st < s_hi; ++st){
      int kb = st*32 + hq*8;
      const f32x4* ap = (const f32x4*)(arow + kb);
      f32x4 x0 = ap[0], x1 = ap[1];
      float a[8] = {x0.x, x0.y, x0.z, x0.w, x1.x, x1.y, x1.z, x1.w};
      short8 ahi, alo;
      #pragma unroll
      for (int e2=0;e2<8;++e2){
        float av = aok ? a[e2] : 0.f;
        unsigned ub = __float_as_uint(av);
        float res = av - __uint_as_float(ub & 0xFFFF0000u);
        ahi[e2] = (short)(ub >> 16);
        alo[e2] = (short)(__float_as_uint(res) >> 16);
      }
      short8 bh0 = *(const short8*)(bh0p + kb);
      short8 bl0 = *(const short8*)(bl0p + kb);
      short8 bh1 = *(const short8*)(bh1p + kb);
      short8 bl1 = *(const short8*)(bl1p + kb);
      acc0 = __builtin_amdgcn_mfma_f32_16x16x32_bf16(ahi, bh0, acc0, 0,0,0);
      acc0 = __builtin_amdgcn_mfma_f32_16x16x32_bf16(alo, bh0, acc0, 0,0,0);
      acc0 = __builtin_amdgcn_mfma_f32_16x16x32_bf16(ahi, bl0, acc0, 0,0,0);
      acc1 = __builtin_amdgcn_mfma_f32_16x16x32_bf16(ahi, bh1, acc1, 0,0,0);
      acc1 = __builtin_amdgcn_mfma_f32_16x16x32_bf16(alo, bh1, acc1, 0,0,0);
      acc1 = __builtin_amdgcn_mfma_f32_16x16x32_bf16(ahi, bl1, acc1, 0,0,0);
    }
    // C/D layout: col = l&15, row = (l>>4)*4 + reg
    #pragma unroll
    for (int i=0;i<4;++i){
      int m = hq*4 + i;
      if (m < 8){
        pbuf[w][m][fc]      = acc0[i];
        pbuf[w][m][16 + fc] = acc1[i];
      }
    }
  }
  __syncthreads();

  // ---- epilogue: reduce partials, root+relu, GRU (threads 0..255) ----
  int node = (t >> 5) & 7, f = t & 31;
  int n2 = nb + node;
  if (t < 256 && n2 < N) htile[node*32 + f] = cur_in[n2*32 + f];
  __syncthreads();
  if (t < 256 && n2 < N){
    float msum = 0.f;
    #pragma unroll
    for (int w2=0; w2<8; ++w2) msum += pbuf[w2][node][f];
    float deg = (float)max(row_off[n2+1] - row_off[n2], 1);
    float rt = 0.f;
    #pragma unroll
    for (int k=0;k<32;++k) rt = fmaf(htile[node*32+k], root_w[k*32+f], rt);
    mtile[node*32 + f] = fmaxf(msum/deg + rt + conv_b[f], 0.f);
  }
  __syncthreads();
  if (t < 256 && n2 < N){
    float gr = bih[f], gz = bih[32+f], gn = bih[64+f];
    float hr = bhh[f], hz = bhh[32+f], hn = bhh[64+f];
    const float* mm = &mtile[node*32];
    const float* hh = &htile[node*32];
    #pragma unroll
    for (int k=0;k<32;++k){
      float mv = mm[k], hv = hh[k];
      gr = fmaf(mv, wih[k*96 + f],      gr);
      gz = fmaf(mv, wih[k*96 + 32 + f], gz);
      gn = fmaf(mv, wih[k*96 + 64 + f], gn);
      hr = fmaf(hv, whh[k*96 + f],      hr);
      hz = fmaf(hv, whh[k*96 + 32 + f], hz);
      hn = fmaf(hv, whh[k*96 + 64 + f], hn);
    }
    float r = sigf(gr + hr);
    float z = sigf(gz + hz);
    float nn2 = tanhf(gn + r*hn);
    cur_out[n2*32 + f] = (1.f - z)*nn2 + z*hh[f];
  }
}

// Set2Set x6 + memory LSTM + FC head; one block per graph; cur cached in regs.
__global__ __launch_bounds__(512) void k_s2s(
    const float* __restrict__ cur,
    const float* __restrict__ wi, const float* __restrict__ wh, const float* __restrict__ sb,
    const float* __restrict__ mwi, const float* __restrict__ mwh, const float* __restrict__ mb,
    const float* __restrict__ hx, const float* __restrict__ cx,
    const float* __restrict__ f1w, const float* __restrict__ f1b,
    const float* __restrict__ f2w, const float* __restrict__ f2b,
    float* __restrict__ out, int N, int G){
  int g = blockIdx.x, t = threadIdx.x;
  int lo = (int)(((long long)g*N + G - 1)/G);
  int hi = (int)(((long long)(g+1)*N + G - 1)/G);
  int cnt = hi - lo;
  __shared__ float qstar[64], hsS[32], csS[32], gbuf[128];
  __shared__ float ebuf[1024];
  __shared__ float redr[8*32];
  __shared__ float smax[8], ssum[8];
  __shared__ float bmaxS, bsumS;
  __shared__ float hnew[32], f1o[32];
  if (t < 64) qstar[t] = 0.f;
  if (t < 32){ hsS[t] = 0.f; csS[t] = 0.f; }
  __syncthreads();
  int wv = t >> 6, l = t & 63, d = l & 31, halfw = l >> 5;
  int p0 = wv*2 + halfw;
  float cv[32];
  #pragma unroll
  for (int i=0;i<32;++i){
    int p = p0 + 16*i;
    cv[i] = (p < cnt) ? cur[(lo + p)*32 + d] : 0.f;
  }
  for (int it = 0; it < 6; ++it){
    if (t < 128){
      float acc = sb[t];
      for (int j=0;j<64;++j) acc = fmaf(qstar[j], wi[j*128+t], acc);
      for (int j=0;j<32;++j) acc = fmaf(hsS[j],  wh[j*128+t], acc);
      gbuf[t] = acc;
    }
    __syncthreads();
    if (t < 32){
      float c = sigf(gbuf[32+t])*csS[t] + sigf(gbuf[t])*tanhf(gbuf[64+t]);
      csS[t] = c;
      hsS[t] = sigf(gbuf[96+t])*tanhf(c);
    }
    __syncthreads();
    float lmax = -1e30f;
    float qd = hsS[d];
    #pragma unroll
    for (int i=0;i<32;++i){
      int p = p0 + 16*i;
      float prod = cv[i]*qd;
      #pragma unroll
      for (int o2 = 1; o2 < 32; o2 <<= 1) prod += __shfl_xor(prod, o2, 64);
      if (p < cnt){
        if (d == 0) ebuf[p] = prod;
        lmax = fmaxf(lmax, prod);
      }
    }
    for (int p = p0 + 512; p < cnt; p += 16){
      float prod = cur[(lo+p)*32+d]*qd;
      for (int o2 = 1; o2 < 32; o2 <<= 1) prod += __shfl_xor(prod, o2, 64);
      if (d == 0) ebuf[p] = prod;
      lmax = fmaxf(lmax, prod);
    }
    #pragma unroll
    for (int o2 = 1; o2 < 64; o2 <<= 1) lmax = fmaxf(lmax, __shfl_xor(lmax, o2, 64));
    if (l == 0) smax[wv] = lmax;
    __syncthreads();
    if (t == 0){ float mm = smax[0]; for (int i=1;i<8;++i) mm = fmaxf(mm, smax[i]); bmaxS = mm; }
    __syncthreads();
    float bmax = bmaxS;
    float asum = 0.f, racc = 0.f;
    #pragma unroll
    for (int i=0;i<32;++i){
      int p = p0 + 16*i;
      if (p < cnt){
        float a = expf(ebuf[p] - bmax);
        if (d == 0) asum += a;
        racc = fmaf(a, cv[i], racc);
      }
    }
    for (int p = p0 + 512; p < cnt; p += 16){
      float a = expf(ebuf[p] - bmax);
      if (d == 0) asum += a;
      racc = fmaf(a, cur[(lo+p)*32+d], racc);
    }
    racc += __shfl_xor(racc, 32, 64);
    #pragma unroll
    for (int o2 = 1; o2 < 64; o2 <<= 1) asum += __shfl_xor(asum, o2, 64);
    if (l < 32) redr[wv*32 + l] = racc;
    if (l == 0) ssum[wv] = asum;
    __syncthreads();
    if (t == 0){ float s2 = 0.f; for (int i=0;i<8;++i) s2 += ssum[i]; bsumS = s2; }
    __syncthreads();
    if (t < 32){
      float rsum = 0.f;
      for (int w2=0; w2<8; ++w2) rsum += redr[w2*32 + t];
      qstar[32 + t] = rsum / bsumS;
      qstar[t] = hsS[t];
    }
    __syncthreads();
  }
  if (t < 128){
    float acc = mb[t];
    for (int j=0;j<64;++j) acc = fmaf(qstar[j], mwi[j*128+t], acc);
    for (int j=0;j<32;++j) acc = fmaf(hx[g*32+j], mwh[j*128+t], acc);
    gbuf[t] = acc;
  }
  __syncthreads();
  if (t < 32){
    float c = sigf(gbuf[32+t])*cx[g*32+t] + sigf(gbuf[t])*tanhf(gbuf[64+t]);
    float h = sigf(gbuf[96+t])*tanhf(c);
    out[G + g*32 + t] = h;
    out[G + G*32 + g*32 + t] = c;
    hnew[t] = h;
  }
  __syncthreads();
  if (t < 32){
    float acc = f1b[t];
    #pragma unroll
    for (int k=0;k<32;++k) acc = fmaf(hnew[k], f1w[k*32+t], acc);
    f1o[t] = fmaxf(acc, 0.f);
  }
  __syncthreads();
  if (t == 0){
    float acc = f2b[0];
    #pragma unroll
    for (int k=0;k<32;++k) acc = fmaf(f1o[k], f2w[k], acc);
    out[g] = acc;
  }
}

extern "C" void kernel_launch(void* const* d_in, const int* in_sizes, int n_in,
                              void* d_out, int out_size, void* d_ws, size_t ws_size,
                              hipStream_t stream) {
  const float* x      = (const float*)d_in[0];
  const float* ea     = (const float*)d_in[1];
  const float* hx     = (const float*)d_in[2];
  const float* cx     = (const float*)d_in[3];
  const float* lin0_w = (const float*)d_in[4];
  const float* lin0_b = (const float*)d_in[5];
  const float* e_w1   = (const float*)d_in[6];
  const float* e_b1   = (const float*)d_in[7];
  const float* e_w2   = (const float*)d_in[8];
  const float* e_b2   = (const float*)d_in[9];
  const float* root_w = (const float*)d_in[10];
  const float* conv_b = (const float*)d_in[11];
  const float* g_wih  = (const float*)d_in[12];
  const float* g_whh  = (const float*)d_in[13];
  const float* g_bih  = (const float*)d_in[14];
  const float* g_bhh  = (const float*)d_in[15];
  const float* s_wi   = (const float*)d_in[16];
  const float* s_wh   = (const float*)d_in[17];
  const float* s_b    = (const float*)d_in[18];
  const float* m_wi   = (const float*)d_in[19];
  const float* m_wh   = (const float*)d_in[20];
  const float* m_b    = (const float*)d_in[21];
  const float* f1w    = (const float*)d_in[22];
  const float* f1b    = (const float*)d_in[23];
  const float* f2w    = (const float*)d_in[24];
  const float* f2b    = (const float*)d_in[25];
  const int*   eidx   = (const int*)d_in[26];
  int N = in_sizes[0]/3;
  int E = in_sizes[1]/4;
  int G = in_sizes[2]/32;
  const int* srcI = eidx;
  const int* dstI = eidx + E;
  float* outF = (float*)d_out;

  char* wbase = (char*)d_ws; size_t off = 0;
  auto carve = [&](size_t nbytes)->char*{
    char* p = wbase + off; off = (off + nbytes + 255) & ~(size_t)255; return p;
  };
  float* cur0    = (float*)carve((size_t)N*32*4);
  float* cur1    = (float*)carve((size_t)N*32*4);
  float* hidp    = (float*)carve((size_t)E*32*4);
  unsigned short* VrT_hi = (unsigned short*)carve((size_t)1056*32*2);
  unsigned short* VrT_lo = (unsigned short*)carve((size_t)1056*32*2);
  int*   counts  = (int*)carve((size_t)N*4);
  int*   cursor  = (int*)carve((size_t)N*4);
  int*   row_off = (int*)carve((size_t)(N+1)*4);
  int*   eid     = (int*)carve((size_t)E*4);
  int*   srcp    = (int*)carve((size_t)E*4);
  (void)ws_size; (void)n_in; (void)out_size;

  // phase A: embeddings + dst-CSR + split/transposed W2 + CSR edge data
  k_init<<<(N+255)/256, 256, 0, stream>>>(counts, cursor, N);
  k_lin0<<<(N*32+255)/256, 256, 0, stream>>>(x, lin0_w, lin0_b, cur0, N);
  k_count<<<(E+255)/256, 256, 0, stream>>>(dstI, counts, E);
  k_scan<<<1, 256, 0, stream>>>(counts, row_off, N);
  k_scatter<<<(E+255)/256, 256, 0, stream>>>(dstI, row_off, cursor, eid, E);
  k_edgeCSR<<<(E*32+255)/256, 256, 0, stream>>>(eid, srcI, ea, e_w1, e_b1, hidp, srcp, E);
  k_permW2split<<<(1056*32+255)/256, 256, 0, stream>>>(e_w2, e_b2, VrT_hi, VrT_lo);

  // phase B: 6 fused message-passing + GRU iterations (ping-pong cur)
  float* cin = cur0; float* cout = cur1;
  for (int it = 0; it < 6; ++it){
    k_iter<<<(N+7)/8, 512, 0, stream>>>(row_off, srcp, hidp, cin, VrT_hi, VrT_lo,
                                        root_w, conv_b, g_wih, g_whh, g_bih, g_bhh,
                                        cout, N);
    float* tmp = cin; cin = cout; cout = tmp;
  }

  // phase C+D: Set2Set x6 + memory LSTM + FC head
  k_s2s<<<G, 512, 0, stream>>>(cin, s_wi, s_wh, s_b, m_wi, m_wh, m_b,
                               hx, cx, f1w, f1b, f2w, f2b, outF, N, G);
}

// Round 4
// 643.603 us; speedup vs baseline: 1.6474x; 1.2237x over previous
//
#include <hip/hip_runtime.h>
#include <math.h>

// CriticBatchNet: NNConv(+edge-net) + GRU x6, Set2Set x6, LSTM head.
// msg[e] = out[src]@W_e[e], W_e[e]=hidden[e]@e_w2+b2
//   => segsum_dst(msg)[m,f] = sum_kd S[m,kd]*Vr[kd,f],
//      S[m,k*32+d] = sum_{e:dst=m} hidden[e,k]*out[src_e,d]
//      S[m,1024+j] = sum_{e:dst=m} out[src_e,j]   (bias rows)
// v4: parallel 3-stage scan (was 1100-barrier single block); k_s2s with
//     LDS-staged cur + thread-per-node dots (no shfl chains); k_iter
//     depth-4 gather prefetch with zero-padded tail; fused k_pre.

typedef __attribute__((ext_vector_type(8))) short short8;
typedef __attribute__((ext_vector_type(4))) float f32x4;

__device__ __forceinline__ float sigf(float x){ return 1.f/(1.f+expf(-x)); }

// fused: zero counts/cursor, lin0, permW2split
__global__ void k_pre(const float* __restrict__ x, const float* __restrict__ w,
                      const float* __restrict__ b,
                      const float* __restrict__ e_w2, const float* __restrict__ e_b2,
                      float* __restrict__ cur, unsigned short* __restrict__ VrT_hi,
                      unsigned short* __restrict__ VrT_lo,
                      int* __restrict__ counts, int* __restrict__ cursor, int N){
  int i = blockIdx.x*blockDim.x + threadIdx.x;
  if (i < N){ counts[i]=0; cursor[i]=0; }
  if (i < N*32){
    int n = i>>5, d = i&31;
    float acc = b[d];
    acc = fmaf(x[n*3+0], w[0*32+d], acc);
    acc = fmaf(x[n*3+1], w[1*32+d], acc);
    acc = fmaf(x[n*3+2], w[2*32+d], acc);
    cur[i] = fmaxf(acc, 0.f);
  }
  if (i < 1056*32){
    int f = i & 31, kd = i >> 5;
    float v = (kd < 1024) ? e_w2[(kd>>5)*1024 + (kd&31)*32 + f]
                          : e_b2[(kd-1024)*32 + f];
    unsigned ub = __float_as_uint(v);
    float res = v - __uint_as_float(ub & 0xFFFF0000u);
    VrT_hi[f*1056 + kd] = (unsigned short)(ub >> 16);
    VrT_lo[f*1056 + kd] = (unsigned short)(__float_as_uint(res) >> 16);
  }
}

__global__ void k_count(const int* __restrict__ dst, int* __restrict__ counts, int E){
  int i = blockIdx.x*blockDim.x + threadIdx.x;
  if (i < E) atomicAdd(&counts[dst[i]], 1);
}

// 3-stage parallel exclusive scan
__global__ void k_scanA(const int* __restrict__ counts, int* __restrict__ row_off,
                        int* __restrict__ part, int N){
  __shared__ int buf[256];
  int b = blockIdx.x, t = threadIdx.x, base = b*256;
  int v = (base + t < N) ? counts[base + t] : 0;
  buf[t] = v; __syncthreads();
  #pragma unroll
  for (int off = 1; off < 256; off <<= 1){
    int tmp = (t >= off) ? buf[t-off] : 0;
    __syncthreads();
    buf[t] += tmp;
    __syncthreads();
  }
  if (base + t < N) row_off[base + t] = buf[t] - v;   // chunk-local exclusive
  if (t == 255) part[b] = buf[255];
}

__global__ void k_scanB(int* __restrict__ part, int* __restrict__ row_off,
                        int nch, int N){
  __shared__ int buf[256];
  int t = threadIdx.x;
  int v = (t < nch) ? part[t] : 0;
  buf[t] = v; __syncthreads();
  #pragma unroll
  for (int off = 1; off < 256; off <<= 1){
    int tmp = (t >= off) ? buf[t-off] : 0;
    __syncthreads();
    buf[t] += tmp;
    __syncthreads();
  }
  if (t < nch) part[t] = buf[t] - v;                  // exclusive chunk offsets
  if (t == 255) row_off[N] = buf[255];                // total
}

__global__ void k_scanC(int* __restrict__ row_off, const int* __restrict__ part, int N){
  int i = blockIdx.x*256 + threadIdx.x;
  if (i < N) row_off[i] += part[blockIdx.x];
}

__global__ void k_scatter(const int* __restrict__ dst, const int* __restrict__ row_off,
                          int* __restrict__ cursor, int* __restrict__ eid, int E){
  int i = blockIdx.x*blockDim.x + threadIdx.x;
  if (i < E){
    int dn = dst[i];
    int pos = row_off[dn] + atomicAdd(&cursor[dn], 1);
    eid[pos] = i;
  }
}

// fused: hidp[p] = relu(ea[eid[p]] @ e_w1 + e_b1), srcp[p] = src[eid[p]]
__global__ void k_edgeCSR(const int* __restrict__ eid, const int* __restrict__ src,
                          const float* __restrict__ ea, const float* __restrict__ w,
                          const float* __restrict__ b, float* __restrict__ hidp,
                          int* __restrict__ srcp, int E){
  int i = blockIdx.x*blockDim.x + threadIdx.x;
  if (i >= E*32) return;
  int p = i>>5, d = i&31;
  int e = eid[p];
  const float4* ea4 = (const float4*)ea;
  float4 v = ea4[e];
  float acc = b[d];
  acc = fmaf(v.x, w[0*32+d], acc);
  acc = fmaf(v.y, w[1*32+d], acc);
  acc = fmaf(v.z, w[2*32+d], acc);
  acc = fmaf(v.w, w[3*32+d], acc);
  hidp[i] = fmaxf(acc, 0.f);
  if (d == 0) srcp[p] = src[e];
}

__device__ __forceinline__ void op_load(const float* __restrict__ hidp,
                                        const int* __restrict__ srcp,
                                        const float* __restrict__ cur_in,
                                        int pp, int hi, int d, float& H, float& O){
  bool val = pp < hi;
  int idx = val ? pp : (hi > 0 ? hi - 1 : 0);
  float h = hidp[idx*32 + d];
  int s = srcp[idx];
  float o = cur_in[s*32 + d];
  H = val ? h : 0.f;
  O = val ? o : 0.f;
}

__device__ __forceinline__ void op_step(float hc, float oc, float (&acc)[16],
                                        float& aex, int hiL){
  #pragma unroll
  for (int r=0;r<16;++r){
    float hk = __shfl(hc, 2*r + hiL, 64);
    acc[r] = fmaf(hk, oc, acc[r]);
  }
  aex += oc;
}

// Fused per-iteration kernel: S build (LDS) -> MFMA contraction (bf16x3)
//   -> root/relu -> GRU. 8 nodes per 512-thread block (8 waves).
__global__ __launch_bounds__(512) void k_iter(
    const int* __restrict__ row_off, const int* __restrict__ srcp,
    const float* __restrict__ hidp, const float* __restrict__ cur_in,
    const unsigned short* __restrict__ VrT_hi, const unsigned short* __restrict__ VrT_lo,
    const float* __restrict__ root_w, const float* __restrict__ conv_b,
    const float* __restrict__ wih, const float* __restrict__ whh,
    const float* __restrict__ bih, const float* __restrict__ bhh,
    float* __restrict__ cur_out, int N){
  __shared__ __align__(16) float s_lds[8*1056];   // S rows [node][kd]
  __shared__ float pbuf[8][8][32];                // per-wave partial aggr
  __shared__ float mtile[8*32];
  __shared__ float htile[8*32];
  int nb = blockIdx.x*8;
  int t = threadIdx.x;
  int w = t >> 6, l = t & 63, d = l & 31, hiL = l >> 5;

  // ---- phase 1: node n = nb + w; outer-product accumulate S in regs ----
  // depth-4 software pipeline; tail zero-padded (pp>=hi loads as 0 -> no-op)
  int n = nb + w;
  float acc[16];
  #pragma unroll
  for (int r=0;r<16;++r) acc[r]=0.f;
  float aex = 0.f;
  if (n < N){
    int lo = row_off[n], hi = row_off[n+1];
    float hA,oA,hB,oB,hC,oC,hD,oD;
    op_load(hidp,srcp,cur_in, lo+0, hi, d, hA,oA);
    op_load(hidp,srcp,cur_in, lo+1, hi, d, hB,oB);
    op_load(hidp,srcp,cur_in, lo+2, hi, d, hC,oC);
    op_load(hidp,srcp,cur_in, lo+3, hi, d, hD,oD);
    for (int p = lo; p < hi; p += 4){
      op_step(hA,oA,acc,aex,hiL); op_load(hidp,srcp,cur_in, p+4, hi, d, hA,oA);
      op_step(hB,oB,acc,aex,hiL); op_load(hidp,srcp,cur_in, p+5, hi, d, hB,oB);
      op_step(hC,oC,acc,aex,hiL); op_load(hidp,srcp,cur_in, p+6, hi, d, hC,oC);
      op_step(hD,oD,acc,aex,hiL); op_load(hidp,srcp,cur_in, p+7, hi, d, hD,oD);
    }
  }
  {
    float* sp = &s_lds[w*1056];
    #pragma unroll
    for (int r=0;r<16;++r) sp[r*64 + l] = acc[r];
    if (l < 32) sp[1024 + l] = aex;
  }
  __syncthreads();

  // ---- phase 2: MFMA contraction, K split across 8 waves ----
  {
    int fc = l & 15;
    int hq = l >> 4;
    bool aok = fc < 8;
    const float* arow = &s_lds[(fc & 7)*1056];
    const unsigned short* bh0p = VrT_hi + fc*1056;
    const unsigned short* bl0p = VrT_lo + fc*1056;
    const unsigned short* bh1p = VrT_hi + (16+fc)*1056;
    const unsigned short* bl1p = VrT_lo + (16+fc)*1056;
    f32x4 acc0 = {0.f,0.f,0.f,0.f}, acc1 = {0.f,0.f,0.f,0.f};
    int s_lo = w*4, s_hi = (w == 7) ? 33 : w*4 + 4;   // 33 K-steps of 32
    for (int st = s_lo; st < s_hi; ++st){
      int kb = st*32 + hq*8;
      const f32x4* ap = (const f32x4*)(arow + kb);
      f32x4 x0 = ap[0], x1 = ap[1];
      float a[8] = {x0.x, x0.y, x0.z, x0.w, x1.x, x1.y, x1.z, x1.w};
      short8 ahi, alo;
      #pragma unroll
      for (int e2=0;e2<8;++e2){
        float av = aok ? a[e2] : 0.f;
        unsigned ub = __float_as_uint(av);
        float res = av - __uint_as_float(ub & 0xFFFF0000u);
        ahi[e2] = (short)(ub >> 16);
        alo[e2] = (short)(__float_as_uint(res) >> 16);
      }
      short8 bh0 = *(const short8*)(bh0p + kb);
      short8 bl0 = *(const short8*)(bl0p + kb);
      short8 bh1 = *(const short8*)(bh1p + kb);
      short8 bl1 = *(const short8*)(bl1p + kb);
      acc0 = __builtin_amdgcn_mfma_f32_16x16x32_bf16(ahi, bh0, acc0, 0,0,0);
      acc0 = __builtin_amdgcn_mfma_f32_16x16x32_bf16(alo, bh0, acc0, 0,0,0);
      acc0 = __builtin_amdgcn_mfma_f32_16x16x32_bf16(ahi, bl0, acc0, 0,0,0);
      acc1 = __builtin_amdgcn_mfma_f32_16x16x32_bf16(ahi, bh1, acc1, 0,0,0);
      acc1 = __builtin_amdgcn_mfma_f32_16x16x32_bf16(alo, bh1, acc1, 0,0,0);
      acc1 = __builtin_amdgcn_mfma_f32_16x16x32_bf16(ahi, bl1, acc1, 0,0,0);
    }
    // C/D layout: col = l&15, row = (l>>4)*4 + reg
    #pragma unroll
    for (int i=0;i<4;++i){
      int m = hq*4 + i;
      if (m < 8){
        pbuf[w][m][fc]      = acc0[i];
        pbuf[w][m][16 + fc] = acc1[i];
      }
    }
  }
  __syncthreads();

  // ---- epilogue: reduce partials, root+relu, GRU (threads 0..255) ----
  int node = (t >> 5) & 7, f = t & 31;
  int n2 = nb + node;
  if (t < 256 && n2 < N) htile[node*32 + f] = cur_in[n2*32 + f];
  __syncthreads();
  if (t < 256 && n2 < N){
    float msum = 0.f;
    #pragma unroll
    for (int w2=0; w2<8; ++w2) msum += pbuf[w2][node][f];
    float deg = (float)max(row_off[n2+1] - row_off[n2], 1);
    float rt = 0.f;
    #pragma unroll
    for (int k=0;k<32;++k) rt = fmaf(htile[node*32+k], root_w[k*32+f], rt);
    mtile[node*32 + f] = fmaxf(msum/deg + rt + conv_b[f], 0.f);
  }
  __syncthreads();
  if (t < 256 && n2 < N){
    float gr = bih[f], gz = bih[32+f], gn = bih[64+f];
    float hr = bhh[f], hz = bhh[32+f], hn = bhh[64+f];
    const float* mm = &mtile[node*32];
    const float* hh = &htile[node*32];
    #pragma unroll
    for (int k=0;k<32;++k){
      float mv = mm[k], hv = hh[k];
      gr = fmaf(mv, wih[k*96 + f],      gr);
      gz = fmaf(mv, wih[k*96 + 32 + f], gz);
      gn = fmaf(mv, wih[k*96 + 64 + f], gn);
      hr = fmaf(hv, whh[k*96 + f],      hr);
      hz = fmaf(hv, whh[k*96 + 32 + f], hz);
      hn = fmaf(hv, whh[k*96 + 64 + f], hn);
    }
    float r = sigf(gr + hr);
    float z = sigf(gz + hz);
    float nn2 = tanhf(gn + r*hn);
    cur_out[n2*32 + f] = (1.f - z)*nn2 + z*hh[f];
  }
}

// Set2Set x6 + memory LSTM + FC head; one block per graph.
// cur slice staged in LDS (stride 33 -> conflict-free); thread-per-node dots.
#define S2S_CAP 544
__global__ __launch_bounds__(512) void k_s2s(
    const float* __restrict__ cur,
    const float* __restrict__ wi, const float* __restrict__ wh, const float* __restrict__ sb,
    const float* __restrict__ mwi, const float* __restrict__ mwh, const float* __restrict__ mb,
    const float* __restrict__ hx, const float* __restrict__ cx,
    const float* __restrict__ f1w, const float* __restrict__ f1b,
    const float* __restrict__ f2w, const float* __restrict__ f2b,
    float* __restrict__ out, int N, int G){
  int g = blockIdx.x, t = threadIdx.x;
  int lo = (int)(((long long)g*N + G - 1)/G);
  int hi = (int)(((long long)(g+1)*N + G - 1)/G);
  int cnt = hi - lo;                 // <= S2S_CAP assumed (N=15000,G=32 -> 469)
  __shared__ float curL[S2S_CAP*33];
  __shared__ float ebuf[S2S_CAP];
  __shared__ float qstar[64], hsS[32], csS[32], gbuf[128];
  __shared__ float redr[8*32];
  __shared__ float smax[8], ssum[8];
  __shared__ float bmaxS, bsumS;
  __shared__ float hnew[32], f1o[32];
  // stage cur slice (coalesced global, padded LDS)
  for (int i = t; i < cnt*32; i += 512){
    int p = i >> 5, d2 = i & 31;
    curL[p*33 + d2] = cur[(size_t)(lo + p)*32 + d2];
  }
  if (t < 64) qstar[t] = 0.f;
  if (t < 32){ hsS[t] = 0.f; csS[t] = 0.f; }
  __syncthreads();
  int wv = t >> 6, l = t & 63, d = l & 31, halfw = l >> 5;
  int p0 = wv*2 + halfw;
  for (int it = 0; it < 6; ++it){
    if (t < 128){
      float acc = sb[t];
      for (int j=0;j<64;++j) acc = fmaf(qstar[j], wi[j*128+t], acc);
      for (int j=0;j<32;++j) acc = fmaf(hsS[j],  wh[j*128+t], acc);
      gbuf[t] = acc;
    }
    __syncthreads();
    if (t < 32){
      float c = sigf(gbuf[32+t])*csS[t] + sigf(gbuf[t])*tanhf(gbuf[64+t]);
      csS[t] = c;
      hsS[t] = sigf(gbuf[96+t])*tanhf(c);
    }
    __syncthreads();
    // pass 1: e[p] = <curL[p], q>; thread-per-node, no shuffles
    float lmax = -3.4e38f;
    for (int p = t; p < cnt; p += 512){
      float acc = 0.f;
      #pragma unroll
      for (int d2=0; d2<32; ++d2) acc = fmaf(curL[p*33 + d2], hsS[d2], acc);
      ebuf[p] = acc;
      lmax = fmaxf(lmax, acc);
    }
    #pragma unroll
    for (int o2 = 1; o2 < 64; o2 <<= 1) lmax = fmaxf(lmax, __shfl_xor(lmax, o2, 64));
    if (l == 0) smax[wv] = lmax;
    __syncthreads();
    if (t == 0){ float mm = smax[0]; for (int i=1;i<8;++i) mm = fmaxf(mm, smax[i]); bmaxS = mm; }
    __syncthreads();
    float bmax = bmaxS;
    // pass 2: a = exp(e-max); block sum
    float lsum = 0.f;
    for (int p = t; p < cnt; p += 512){
      float a = expf(ebuf[p] - bmax);
      ebuf[p] = a;
      lsum += a;
    }
    #pragma unroll
    for (int o2 = 1; o2 < 64; o2 <<= 1) lsum += __shfl_xor(lsum, o2, 64);
    if (l == 0) ssum[wv] = lsum;
    __syncthreads();
    if (t == 0){ float s2 = 0.f; for (int i=0;i<8;++i) s2 += ssum[i]; bsumS = s2; }
    __syncthreads();
    // r[d] = sum_p a[p] * curL[p][d]  (a via LDS broadcast)
    float racc = 0.f;
    for (int p = p0; p < cnt; p += 16)
      racc = fmaf(ebuf[p], curL[p*33 + d], racc);
    racc += __shfl_xor(racc, 32, 64);
    if (l < 32) redr[wv*32 + l] = racc;
    __syncthreads();
    if (t < 32){
      float rsum = 0.f;
      #pragma unroll
      for (int w2=0; w2<8; ++w2) rsum += redr[w2*32 + t];
      qstar[32 + t] = rsum / bsumS;
      qstar[t] = hsS[t];
    }
    __syncthreads();
  }
  // memory LSTM + FC head
  if (t < 128){
    float acc = mb[t];
    for (int j=0;j<64;++j) acc = fmaf(qstar[j], mwi[j*128+t], acc);
    for (int j=0;j<32;++j) acc = fmaf(hx[g*32+j], mwh[j*128+t], acc);
    gbuf[t] = acc;
  }
  __syncthreads();
  if (t < 32){
    float c = sigf(gbuf[32+t])*cx[g*32+t] + sigf(gbuf[t])*tanhf(gbuf[64+t]);
    float h = sigf(gbuf[96+t])*tanhf(c);
    out[G + g*32 + t] = h;
    out[G + G*32 + g*32 + t] = c;
    hnew[t] = h;
  }
  __syncthreads();
  if (t < 32){
    float acc = f1b[t];
    #pragma unroll
    for (int k=0;k<32;++k) acc = fmaf(hnew[k], f1w[k*32+t], acc);
    f1o[t] = fmaxf(acc, 0.f);
  }
  __syncthreads();
  if (t == 0){
    float acc = f2b[0];
    #pragma unroll
    for (int k=0;k<32;++k) acc = fmaf(f1o[k], f2w[k], acc);
    out[g] = acc;
  }
}

extern "C" void kernel_launch(void* const* d_in, const int* in_sizes, int n_in,
                              void* d_out, int out_size, void* d_ws, size_t ws_size,
                              hipStream_t stream) {
  const float* x      = (const float*)d_in[0];
  const float* ea     = (const float*)d_in[1];
  const float* hx     = (const float*)d_in[2];
  const float* cx     = (const float*)d_in[3];
  const float* lin0_w = (const float*)d_in[4];
  const float* lin0_b = (const float*)d_in[5];
  const float* e_w1   = (const float*)d_in[6];
  const float* e_b1   = (const float*)d_in[7];
  const float* e_w2   = (const float*)d_in[8];
  const float* e_b2   = (const float*)d_in[9];
  const float* root_w = (const float*)d_in[10];
  const float* conv_b = (const float*)d_in[11];
  const float* g_wih  = (const float*)d_in[12];
  const float* g_whh  = (const float*)d_in[13];
  const float* g_bih  = (const float*)d_in[14];
  const float* g_bhh  = (const float*)d_in[15];
  const float* s_wi   = (const float*)d_in[16];
  const float* s_wh   = (const float*)d_in[17];
  const float* s_b    = (const float*)d_in[18];
  const float* m_wi   = (const float*)d_in[19];
  const float* m_wh   = (const float*)d_in[20];
  const float* m_b    = (const float*)d_in[21];
  const float* f1w    = (const float*)d_in[22];
  const float* f1b    = (const float*)d_in[23];
  const float* f2w    = (const float*)d_in[24];
  const float* f2b    = (const float*)d_in[25];
  const int*   eidx   = (const int*)d_in[26];
  int N = in_sizes[0]/3;
  int E = in_sizes[1]/4;
  int G = in_sizes[2]/32;
  const int* srcI = eidx;
  const int* dstI = eidx + E;
  float* outF = (float*)d_out;

  char* wbase = (char*)d_ws; size_t off = 0;
  auto carve = [&](size_t nbytes)->char*{
    char* p = wbase + off; off = (off + nbytes + 255) & ~(size_t)255; return p;
  };
  float* cur0    = (float*)carve((size_t)N*32*4);
  float* cur1    = (float*)carve((size_t)N*32*4);
  float* hidp    = (float*)carve((size_t)E*32*4);
  unsigned short* VrT_hi = (unsigned short*)carve((size_t)1056*32*2);
  unsigned short* VrT_lo = (unsigned short*)carve((size_t)1056*32*2);
  int*   counts  = (int*)carve((size_t)N*4);
  int*   cursor  = (int*)carve((size_t)N*4);
  int*   row_off = (int*)carve((size_t)(N+1)*4);
  int*   eid     = (int*)carve((size_t)E*4);
  int*   srcp    = (int*)carve((size_t)E*4);
  int*   part    = (int*)carve((size_t)256*4);
  (void)ws_size; (void)n_in; (void)out_size;

  int nch = (N + 255)/256;

  // phase A: fused pre (init+lin0+W2 split), CSR build with parallel scan
  k_pre<<<(N*32+255)/256, 256, 0, stream>>>(x, lin0_w, lin0_b, e_w2, e_b2,
                                            cur0, VrT_hi, VrT_lo, counts, cursor, N);
  k_count<<<(E+255)/256, 256, 0, stream>>>(dstI, counts, E);
  k_scanA<<<nch, 256, 0, stream>>>(counts, row_off, part, N);
  k_scanB<<<1, 256, 0, stream>>>(part, row_off, nch, N);
  k_scanC<<<nch, 256, 0, stream>>>(row_off, part, N);
  k_scatter<<<(E+255)/256, 256, 0, stream>>>(dstI, row_off, cursor, eid, E);
  k_edgeCSR<<<(E*32+255)/256, 256, 0, stream>>>(eid, srcI, ea, e_w1, e_b1, hidp, srcp, E);

  // phase B: 6 fused message-passing + GRU iterations (ping-pong cur)
  float* cin = cur0; float* cout = cur1;
  for (int it = 0; it < 6; ++it){
    k_iter<<<(N+7)/8, 512, 0, stream>>>(row_off, srcp, hidp, cin, VrT_hi, VrT_lo,
                                        root_w, conv_b, g_wih, g_whh, g_bih, g_bhh,
                                        cout, N);
    float* tmp = cin; cin = cout; cout = tmp;
  }

  // phase C+D: Set2Set x6 + memory LSTM + FC head
  k_s2s<<<G, 512, 0, stream>>>(cin, s_wi, s_wh, s_b, m_wi, m_wh, m_b,
                               hx, cx, f1w, f1b, f2w, f2b, outF, N, G);
}

// Round 5
// 411.004 us; speedup vs baseline: 2.5798x; 1.5659x over previous
//
#include <hip/hip_runtime.h>
#include <math.h>

// CriticBatchNet: NNConv(+edge-net) + GRU x6, Set2Set x6, LSTM head.
// msg[e] = out[src]@W_e[e], W_e[e]=hidden[e]@e_w2+b2
//   => segsum_dst(msg)[m,f] = sum_kd S[m,kd]*Vr[kd,f],
//      S[m,k*32+d] = sum_{e:dst=m} hidden[e,k]*out[src_e,d]
//      S[m,1024+j] = sum_{e:dst=m} out[src_e,j]   (bias rows)
// v5: phase-1 S build via MFMA 32x32x16 bf16x3 over 16-edge chunks
//     (replaces 16 ds_bpermute per edge); hidp and S stored as packed
//     split-bf16 (hi16|lo16); 256-thread blocks, partials reuse s_lds
//     -> 4 blocks/CU; S row stride padded 1056->1060 (8-way -> 4-way).

typedef __attribute__((ext_vector_type(8))) short short8;
typedef __attribute__((ext_vector_type(4))) float f32x4;
typedef __attribute__((ext_vector_type(16))) float f32x16;

#define S_PAD 1060

__device__ __forceinline__ float sigf(float x){ return 1.f/(1.f+expf(-x)); }

__device__ __forceinline__ unsigned packsplit(float v){
  unsigned uv = __float_as_uint(v);
  float res = v - __uint_as_float(uv & 0xFFFF0000u);
  return (uv & 0xFFFF0000u) | (__float_as_uint(res) >> 16);
}

// fused: zero counts/cursor, lin0, permW2split
__global__ void k_pre(const float* __restrict__ x, const float* __restrict__ w,
                      const float* __restrict__ b,
                      const float* __restrict__ e_w2, const float* __restrict__ e_b2,
                      float* __restrict__ cur, unsigned short* __restrict__ VrT_hi,
                      unsigned short* __restrict__ VrT_lo,
                      int* __restrict__ counts, int* __restrict__ cursor, int N){
  int i = blockIdx.x*blockDim.x + threadIdx.x;
  if (i < N){ counts[i]=0; cursor[i]=0; }
  if (i < N*32){
    int n = i>>5, d = i&31;
    float acc = b[d];
    acc = fmaf(x[n*3+0], w[0*32+d], acc);
    acc = fmaf(x[n*3+1], w[1*32+d], acc);
    acc = fmaf(x[n*3+2], w[2*32+d], acc);
    cur[i] = fmaxf(acc, 0.f);
  }
  if (i < 1056*32){
    int f = i & 31, kd = i >> 5;
    float v = (kd < 1024) ? e_w2[(kd>>5)*1024 + (kd&31)*32 + f]
                          : e_b2[(kd-1024)*32 + f];
    unsigned ub = __float_as_uint(v);
    float res = v - __uint_as_float(ub & 0xFFFF0000u);
    VrT_hi[f*1056 + kd] = (unsigned short)(ub >> 16);
    VrT_lo[f*1056 + kd] = (unsigned short)(__float_as_uint(res) >> 16);
  }
}

__global__ void k_count(const int* __restrict__ dst, int* __restrict__ counts, int E){
  int i = blockIdx.x*blockDim.x + threadIdx.x;
  if (i < E) atomicAdd(&counts[dst[i]], 1);
}

// 3-stage parallel exclusive scan
__global__ void k_scanA(const int* __restrict__ counts, int* __restrict__ row_off,
                        int* __restrict__ part, int N){
  __shared__ int buf[256];
  int b = blockIdx.x, t = threadIdx.x, base = b*256;
  int v = (base + t < N) ? counts[base + t] : 0;
  buf[t] = v; __syncthreads();
  #pragma unroll
  for (int off = 1; off < 256; off <<= 1){
    int tmp = (t >= off) ? buf[t-off] : 0;
    __syncthreads();
    buf[t] += tmp;
    __syncthreads();
  }
  if (base + t < N) row_off[base + t] = buf[t] - v;
  if (t == 255) part[b] = buf[255];
}

__global__ void k_scanB(int* __restrict__ part, int* __restrict__ row_off,
                        int nch, int N){
  __shared__ int buf[256];
  int t = threadIdx.x;
  int v = (t < nch) ? part[t] : 0;
  buf[t] = v; __syncthreads();
  #pragma unroll
  for (int off = 1; off < 256; off <<= 1){
    int tmp = (t >= off) ? buf[t-off] : 0;
    __syncthreads();
    buf[t] += tmp;
    __syncthreads();
  }
  if (t < nch) part[t] = buf[t] - v;
  if (t == 255) row_off[N] = buf[255];
}

__global__ void k_scanC(int* __restrict__ row_off, const int* __restrict__ part, int N){
  int i = blockIdx.x*256 + threadIdx.x;
  if (i < N) row_off[i] += part[blockIdx.x];
}

__global__ void k_scatter(const int* __restrict__ dst, const int* __restrict__ row_off,
                          int* __restrict__ cursor, int* __restrict__ eid, int E){
  int i = blockIdx.x*blockDim.x + threadIdx.x;
  if (i < E){
    int dn = dst[i];
    int pos = row_off[dn] + atomicAdd(&cursor[dn], 1);
    eid[pos] = i;
  }
}

// fused: hidq[p] = packsplit(relu(ea[eid[p]] @ e_w1 + e_b1)), srcp[p] = src[eid[p]]
__global__ void k_edgeCSR(const int* __restrict__ eid, const int* __restrict__ src,
                          const float* __restrict__ ea, const float* __restrict__ w,
                          const float* __restrict__ b, unsigned* __restrict__ hidq,
                          int* __restrict__ srcp, int E){
  int i = blockIdx.x*blockDim.x + threadIdx.x;
  if (i >= E*32) return;
  int p = i>>5, d = i&31;
  int e = eid[p];
  const float4* ea4 = (const float4*)ea;
  float4 v = ea4[e];
  float acc = b[d];
  acc = fmaf(v.x, w[0*32+d], acc);
  acc = fmaf(v.y, w[1*32+d], acc);
  acc = fmaf(v.z, w[2*32+d], acc);
  acc = fmaf(v.w, w[3*32+d], acc);
  hidq[i] = packsplit(fmaxf(acc, 0.f));
  if (d == 0) srcp[p] = src[e];
}

// Fused per-iteration kernel: 256 threads, 8 nodes (2 per wave in phase 1).
// phase 1: S[n] = H_e^T @ O_e via mfma_32x32x16_bf16 (x3 split), 16-edge chunks
// phase 2: aggr = S @ Vr via mfma_16x16x32_bf16 (x3), K split across 4 waves
// epilogue: reduce partials, root+relu, GRU.
__global__ __launch_bounds__(256) void k_iter(
    const int* __restrict__ row_off, const int* __restrict__ srcp,
    const unsigned* __restrict__ hidq, const float* __restrict__ cur_in,
    const unsigned short* __restrict__ VrT_hi, const unsigned short* __restrict__ VrT_lo,
    const float* __restrict__ root_w, const float* __restrict__ conv_b,
    const float* __restrict__ wih, const float* __restrict__ whh,
    const float* __restrict__ bih, const float* __restrict__ bhh,
    float* __restrict__ cur_out, int N){
  __shared__ __align__(16) unsigned s_lds[8*S_PAD];  // packed split-bf16 S rows
  __shared__ float htile[8*32];
  __shared__ float mtile[8*32];
  int nb = blockIdx.x*8;
  int t = threadIdx.x;
  int w = t >> 6, l = t & 63, col = l & 31, half = l >> 5;

  // stage htile (h for GRU/root) early — overlaps phase 1
  {
    int node = t >> 5, f = t & 31;
    int n2 = nb + node;
    htile[t] = (n2 < N) ? cur_in[n2*32 + f] : 0.f;
  }

  // ---- phase 1: 2 nodes per wave, MFMA outer-product accumulation ----
  for (int q = 0; q < 2; ++q){
    int n = nb + w*2 + q;
    f32x16 Sacc = {0.f,0.f,0.f,0.f,0.f,0.f,0.f,0.f,
                   0.f,0.f,0.f,0.f,0.f,0.f,0.f,0.f};
    float aexp = 0.f;
    int lo = 0, hi = 0;
    if (n < N){ lo = row_off[n]; hi = row_off[n+1]; }
    for (int p0 = lo; p0 < hi; p0 += 16){
      short8 Ah, Al, Bh, Bl;
      #pragma unroll
      for (int j=0;j<8;++j){
        int pp = p0 + 8*half + j;
        bool val = pp < hi;
        int idx = val ? pp : lo;
        unsigned hp = hidq[idx*32 + col];         // A[k=col][edge] packed
        int s = srcp[idx];
        float ov = cur_in[s*32 + col];            // B[edge][d=col]
        ov = val ? ov : 0.f;
        Ah[j] = (short)(hp >> 16);
        Al[j] = (short)(hp & 0xffffu);
        unsigned uo = __float_as_uint(ov);
        float ores = ov - __uint_as_float(uo & 0xFFFF0000u);
        Bh[j] = (short)(uo >> 16);
        Bl[j] = (short)(__float_as_uint(ores) >> 16);
        aexp += ov;
      }
      Sacc = __builtin_amdgcn_mfma_f32_32x32x16_bf16(Ah, Bh, Sacc, 0,0,0);
      Sacc = __builtin_amdgcn_mfma_f32_32x32x16_bf16(Al, Bh, Sacc, 0,0,0);
      Sacc = __builtin_amdgcn_mfma_f32_32x32x16_bf16(Ah, Bl, Sacc, 0,0,0);
    }
    // write packed split S row: C row=(i&3)+8*(i>>2)+4*half (k), col=d
    unsigned* sp = &s_lds[(w*2+q)*S_PAD];
    #pragma unroll
    for (int i=0;i<16;++i){
      int k = (i&3) + 8*(i>>2) + 4*half;
      sp[k*32 + col] = packsplit(Sacc[i]);
    }
    aexp += __shfl_xor(aexp, 32, 64);
    if (l < 32) sp[1024 + l] = packsplit(aexp);
  }
  __syncthreads();

  // ---- phase 2: C[m][f] = sum_kd S[m][kd]*Vr[kd][f], 33 K-steps / 4 waves ----
  int fc = l & 15, hq = l >> 4;
  const unsigned* arow = &s_lds[(fc & 7)*S_PAD];
  const unsigned short* bh0p = VrT_hi + fc*1056;
  const unsigned short* bl0p = VrT_lo + fc*1056;
  const unsigned short* bh1p = VrT_hi + (16+fc)*1056;
  const unsigned short* bl1p = VrT_lo + (16+fc)*1056;
  f32x4 acc0 = {0.f,0.f,0.f,0.f}, acc1 = {0.f,0.f,0.f,0.f};
  int s_lo = w*9, s_hi = min(33, w*9+9);
  for (int st = s_lo; st < s_hi; ++st){
    int kb = st*32 + hq*8;
    const uint4* ap = (const uint4*)(arow + kb);
    uint4 ua = ap[0], ub = ap[1];
    short8 Ah, Al;
    Ah[0]=(short)(ua.x>>16); Al[0]=(short)(ua.x & 0xffffu);
    Ah[1]=(short)(ua.y>>16); Al[1]=(short)(ua.y & 0xffffu);
    Ah[2]=(short)(ua.z>>16); Al[2]=(short)(ua.z & 0xffffu);
    Ah[3]=(short)(ua.w>>16); Al[3]=(short)(ua.w & 0xffffu);
    Ah[4]=(short)(ub.x>>16); Al[4]=(short)(ub.x & 0xffffu);
    Ah[5]=(short)(ub.y>>16); Al[5]=(short)(ub.y & 0xffffu);
    Ah[6]=(short)(ub.z>>16); Al[6]=(short)(ub.z & 0xffffu);
    Ah[7]=(short)(ub.w>>16); Al[7]=(short)(ub.w & 0xffffu);
    short8 bh0 = *(const short8*)(bh0p + kb);
    short8 bl0 = *(const short8*)(bl0p + kb);
    short8 bh1 = *(const short8*)(bh1p + kb);
    short8 bl1 = *(const short8*)(bl1p + kb);
    acc0 = __builtin_amdgcn_mfma_f32_16x16x32_bf16(Ah, bh0, acc0, 0,0,0);
    acc0 = __builtin_amdgcn_mfma_f32_16x16x32_bf16(Al, bh0, acc0, 0,0,0);
    acc0 = __builtin_amdgcn_mfma_f32_16x16x32_bf16(Ah, bl0, acc0, 0,0,0);
    acc1 = __builtin_amdgcn_mfma_f32_16x16x32_bf16(Ah, bh1, acc1, 0,0,0);
    acc1 = __builtin_amdgcn_mfma_f32_16x16x32_bf16(Al, bh1, acc1, 0,0,0);
    acc1 = __builtin_amdgcn_mfma_f32_16x16x32_bf16(Ah, bl1, acc1, 0,0,0);
  }
  __syncthreads();                       // all s_lds reads done
  float* pbuf = (float*)s_lds;           // reuse: [w][m<8][32f]
  #pragma unroll
  for (int i=0;i<4;++i){
    int m = hq*4 + i;                    // C row = node; only hq==0 has m<4.. m<8 via hq 0,1
    if (m < 8){
      pbuf[(w*8 + m)*32 + fc]      = acc0[i];
      pbuf[(w*8 + m)*32 + 16 + fc] = acc1[i];
    }
  }
  __syncthreads();

  // ---- epilogue: reduce partials, root+relu -> m, then GRU ----
  int node = t >> 5, f = t & 31;
  int n2 = nb + node;
  if (n2 < N){
    float msum = pbuf[node*32 + f] + pbuf[node*32 + f + 256]
               + pbuf[node*32 + f + 512] + pbuf[node*32 + f + 768];
    float deg = (float)max(row_off[n2+1] - row_off[n2], 1);
    float rt = 0.f;
    #pragma unroll
    for (int k=0;k<32;++k) rt = fmaf(htile[node*32+k], root_w[k*32+f], rt);
    mtile[node*32 + f] = fmaxf(msum/deg + rt + conv_b[f], 0.f);
  }
  __syncthreads();
  if (n2 < N){
    float gr = bih[f], gz = bih[32+f], gn = bih[64+f];
    float hr = bhh[f], hz = bhh[32+f], hn = bhh[64+f];
    const float* mm = &mtile[node*32];
    const float* hh = &htile[node*32];
    #pragma unroll
    for (int k=0;k<32;++k){
      float mv = mm[k], hv = hh[k];
      gr = fmaf(mv, wih[k*96 + f],      gr);
      gz = fmaf(mv, wih[k*96 + 32 + f], gz);
      gn = fmaf(mv, wih[k*96 + 64 + f], gn);
      hr = fmaf(hv, whh[k*96 + f],      hr);
      hz = fmaf(hv, whh[k*96 + 32 + f], hz);
      hn = fmaf(hv, whh[k*96 + 64 + f], hn);
    }
    float r = sigf(gr + hr);
    float z = sigf(gz + hz);
    float nn2 = tanhf(gn + r*hn);
    cur_out[n2*32 + f] = (1.f - z)*nn2 + z*hh[f];
  }
}

// Set2Set x6 + memory LSTM + FC head; one block per graph.
#define S2S_CAP 544
__global__ __launch_bounds__(512) void k_s2s(
    const float* __restrict__ cur,
    const float* __restrict__ wi, const float* __restrict__ wh, const float* __restrict__ sb,
    const float* __restrict__ mwi, const float* __restrict__ mwh, const float* __restrict__ mb,
    const float* __restrict__ hx, const float* __restrict__ cx,
    const float* __restrict__ f1w, const float* __restrict__ f1b,
    const float* __restrict__ f2w, const float* __restrict__ f2b,
    float* __restrict__ out, int N, int G){
  int g = blockIdx.x, t = threadIdx.x;
  int lo = (int)(((long long)g*N + G - 1)/G);
  int hi = (int)(((long long)(g+1)*N + G - 1)/G);
  int cnt = hi - lo;
  __shared__ float curL[S2S_CAP*33];
  __shared__ float ebuf[S2S_CAP];
  __shared__ float qstar[64], hsS[32], csS[32], gbuf[128];
  __shared__ float redr[8*32];
  __shared__ float smax[8], ssum[8];
  __shared__ float bmaxS, bsumS;
  __shared__ float hnew[32], f1o[32];
  for (int i = t; i < cnt*32; i += 512){
    int p = i >> 5, d2 = i & 31;
    curL[p*33 + d2] = cur[(size_t)(lo + p)*32 + d2];
  }
  if (t < 64) qstar[t] = 0.f;
  if (t < 32){ hsS[t] = 0.f; csS[t] = 0.f; }
  __syncthreads();
  int wv = t >> 6, l = t & 63, d = l & 31, halfw = l >> 5;
  int p0 = wv*2 + halfw;
  for (int it = 0; it < 6; ++it){
    if (t < 128){
      float acc = sb[t];
      for (int j=0;j<64;++j) acc = fmaf(qstar[j], wi[j*128+t], acc);
      for (int j=0;j<32;++j) acc = fmaf(hsS[j],  wh[j*128+t], acc);
      gbuf[t] = acc;
    }
    __syncthreads();
    if (t < 32){
      float c = sigf(gbuf[32+t])*csS[t] + sigf(gbuf[t])*tanhf(gbuf[64+t]);
      csS[t] = c;
      hsS[t] = sigf(gbuf[96+t])*tanhf(c);
    }
    __syncthreads();
    float lmax = -3.4e38f;
    for (int p = t; p < cnt; p += 512){
      float acc = 0.f;
      #pragma unroll
      for (int d2=0; d2<32; ++d2) acc = fmaf(curL[p*33 + d2], hsS[d2], acc);
      ebuf[p] = acc;
      lmax = fmaxf(lmax, acc);
    }
    #pragma unroll
    for (int o2 = 1; o2 < 64; o2 <<= 1) lmax = fmaxf(lmax, __shfl_xor(lmax, o2, 64));
    if (l == 0) smax[wv] = lmax;
    __syncthreads();
    if (t == 0){ float mm = smax[0]; for (int i=1;i<8;++i) mm = fmaxf(mm, smax[i]); bmaxS = mm; }
    __syncthreads();
    float bmax = bmaxS;
    float lsum = 0.f;
    for (int p = t; p < cnt; p += 512){
      float a = expf(ebuf[p] - bmax);
      ebuf[p] = a;
      lsum += a;
    }
    #pragma unroll
    for (int o2 = 1; o2 < 64; o2 <<= 1) lsum += __shfl_xor(lsum, o2, 64);
    if (l == 0) ssum[wv] = lsum;
    __syncthreads();
    if (t == 0){ float s2 = 0.f; for (int i=0;i<8;++i) s2 += ssum[i]; bsumS = s2; }
    __syncthreads();
    float racc = 0.f;
    for (int p = p0; p < cnt; p += 16)
      racc = fmaf(ebuf[p], curL[p*33 + d], racc);
    racc += __shfl_xor(racc, 32, 64);
    if (l < 32) redr[wv*32 + l] = racc;
    __syncthreads();
    if (t < 32){
      float rsum = 0.f;
      #pragma unroll
      for (int w2=0; w2<8; ++w2) rsum += redr[w2*32 + t];
      qstar[32 + t] = rsum / bsumS;
      qstar[t] = hsS[t];
    }
    __syncthreads();
  }
  if (t < 128){
    float acc = mb[t];
    for (int j=0;j<64;++j) acc = fmaf(qstar[j], mwi[j*128+t], acc);
    for (int j=0;j<32;++j) acc = fmaf(hx[g*32+j], mwh[j*128+t], acc);
    gbuf[t] = acc;
  }
  __syncthreads();
  if (t < 32){
    float c = sigf(gbuf[32+t])*cx[g*32+t] + sigf(gbuf[t])*tanhf(gbuf[64+t]);
    float h = sigf(gbuf[96+t])*tanhf(c);
    out[G + g*32 + t] = h;
    out[G + G*32 + g*32 + t] = c;
    hnew[t] = h;
  }
  __syncthreads();
  if (t < 32){
    float acc = f1b[t];
    #pragma unroll
    for (int k=0;k<32;++k) acc = fmaf(hnew[k], f1w[k*32+t], acc);
    f1o[t] = fmaxf(acc, 0.f);
  }
  __syncthreads();
  if (t == 0){
    float acc = f2b[0];
    #pragma unroll
    for (int k=0;k<32;++k) acc = fmaf(f1o[k], f2w[k], acc);
    out[g] = acc;
  }
}

extern "C" void kernel_launch(void* const* d_in, const int* in_sizes, int n_in,
                              void* d_out, int out_size, void* d_ws, size_t ws_size,
                              hipStream_t stream) {
  const float* x      = (const float*)d_in[0];
  const float* ea     = (const float*)d_in[1];
  const float* hx     = (const float*)d_in[2];
  const float* cx     = (const float*)d_in[3];
  const float* lin0_w = (const float*)d_in[4];
  const float* lin0_b = (const float*)d_in[5];
  const float* e_w1   = (const float*)d_in[6];
  const float* e_b1   = (const float*)d_in[7];
  const float* e_w2   = (const float*)d_in[8];
  const float* e_b2   = (const float*)d_in[9];
  const float* root_w = (const float*)d_in[10];
  const float* conv_b = (const float*)d_in[11];
  const float* g_wih  = (const float*)d_in[12];
  const float* g_whh  = (const float*)d_in[13];
  const float* g_bih  = (const float*)d_in[14];
  const float* g_bhh  = (const float*)d_in[15];
  const float* s_wi   = (const float*)d_in[16];
  const float* s_wh   = (const float*)d_in[17];
  const float* s_b    = (const float*)d_in[18];
  const float* m_wi   = (const float*)d_in[19];
  const float* m_wh   = (const float*)d_in[20];
  const float* m_b    = (const float*)d_in[21];
  const float* f1w    = (const float*)d_in[22];
  const float* f1b    = (const float*)d_in[23];
  const float* f2w    = (const float*)d_in[24];
  const float* f2b    = (const float*)d_in[25];
  const int*   eidx   = (const int*)d_in[26];
  int N = in_sizes[0]/3;
  int E = in_sizes[1]/4;
  int G = in_sizes[2]/32;
  const int* srcI = eidx;
  const int* dstI = eidx + E;
  float* outF = (float*)d_out;

  char* wbase = (char*)d_ws; size_t off = 0;
  auto carve = [&](size_t nbytes)->char*{
    char* p = wbase + off; off = (off + nbytes + 255) & ~(size_t)255; return p;
  };
  float* cur0    = (float*)carve((size_t)N*32*4);
  float* cur1    = (float*)carve((size_t)N*32*4);
  unsigned* hidq = (unsigned*)carve((size_t)E*32*4);
  unsigned short* VrT_hi = (unsigned short*)carve((size_t)1056*32*2);
  unsigned short* VrT_lo = (unsigned short*)carve((size_t)1056*32*2);
  int*   counts  = (int*)carve((size_t)N*4);
  int*   cursor  = (int*)carve((size_t)N*4);
  int*   row_off = (int*)carve((size_t)(N+1)*4);
  int*   eid     = (int*)carve((size_t)E*4);
  int*   srcp    = (int*)carve((size_t)E*4);
  int*   part    = (int*)carve((size_t)256*4);
  (void)ws_size; (void)n_in; (void)out_size;

  int nch = (N + 255)/256;

  // phase A: fused pre (init+lin0+W2 split), CSR build with parallel scan
  k_pre<<<(N*32+255)/256, 256, 0, stream>>>(x, lin0_w, lin0_b, e_w2, e_b2,
                                            cur0, VrT_hi, VrT_lo, counts, cursor, N);
  k_count<<<(E+255)/256, 256, 0, stream>>>(dstI, counts, E);
  k_scanA<<<nch, 256, 0, stream>>>(counts, row_off, part, N);
  k_scanB<<<1, 256, 0, stream>>>(part, row_off, nch, N);
  k_scanC<<<nch, 256, 0, stream>>>(row_off, part, N);
  k_scatter<<<(E+255)/256, 256, 0, stream>>>(dstI, row_off, cursor, eid, E);
  k_edgeCSR<<<(E*32+255)/256, 256, 0, stream>>>(eid, srcI, ea, e_w1, e_b1, hidq, srcp, E);

  // phase B: 6 fused message-passing + GRU iterations (ping-pong cur)
  float* cin = cur0; float* cout = cur1;
  for (int it = 0; it < 6; ++it){
    k_iter<<<(N+7)/8, 256, 0, stream>>>(row_off, srcp, hidq, cin, VrT_hi, VrT_lo,
                                        root_w, conv_b, g_wih, g_whh, g_bih, g_bhh,
                                        cout, N);
    float* tmp = cin; cin = cout; cout = tmp;
  }

  // phase C+D: Set2Set x6 + memory LSTM + FC head
  k_s2s<<<G, 512, 0, stream>>>(cin, s_wi, s_wh, s_b, m_wi, m_wh, m_b,
                               hx, cx, f1w, f1b, f2w, f2b, outF, N, G);
}

// Round 6
// 400.972 us; speedup vs baseline: 2.6443x; 1.0250x over previous
//
#include <hip/hip_runtime.h>
#include <math.h>

// CriticBatchNet: NNConv(+edge-net) + GRU x6, Set2Set x6, LSTM head.
// msg[e] = out[src]@W_e[e], W_e[e]=hidden[e]@e_w2+b2
//   => segsum_dst(msg)[m,f] = sum_kd S[m,kd]*Vr[kd,f],
//      S[m,k*32+d] = sum_{e:dst=m} hidden[e,k]*out[src_e,d]
//      S[m,1024+j] = sum_{e:dst=m} out[src_e,j]   (bias rows)
// v6: k_iter 16 nodes / 512 threads (full M=16 MFMA rows in phase 2,
//     per-node Vr traffic halved); k_s2s one wave per graph (barrier-free
//     wave-synchronous Set2Set, LSTM cell state in registers).

typedef __attribute__((ext_vector_type(8))) short short8;
typedef __attribute__((ext_vector_type(4))) float f32x4;
typedef __attribute__((ext_vector_type(16))) float f32x16;

#define S_PAD 1060

__device__ __forceinline__ float sigf(float x){ return 1.f/(1.f+expf(-x)); }

__device__ __forceinline__ unsigned packsplit(float v){
  unsigned uv = __float_as_uint(v);
  float res = v - __uint_as_float(uv & 0xFFFF0000u);
  return (uv & 0xFFFF0000u) | (__float_as_uint(res) >> 16);
}

// fused: zero counts/cursor, lin0, permW2split
__global__ void k_pre(const float* __restrict__ x, const float* __restrict__ w,
                      const float* __restrict__ b,
                      const float* __restrict__ e_w2, const float* __restrict__ e_b2,
                      float* __restrict__ cur, unsigned short* __restrict__ VrT_hi,
                      unsigned short* __restrict__ VrT_lo,
                      int* __restrict__ counts, int* __restrict__ cursor, int N){
  int i = blockIdx.x*blockDim.x + threadIdx.x;
  if (i < N){ counts[i]=0; cursor[i]=0; }
  if (i < N*32){
    int n = i>>5, d = i&31;
    float acc = b[d];
    acc = fmaf(x[n*3+0], w[0*32+d], acc);
    acc = fmaf(x[n*3+1], w[1*32+d], acc);
    acc = fmaf(x[n*3+2], w[2*32+d], acc);
    cur[i] = fmaxf(acc, 0.f);
  }
  if (i < 1056*32){
    int f = i & 31, kd = i >> 5;
    float v = (kd < 1024) ? e_w2[(kd>>5)*1024 + (kd&31)*32 + f]
                          : e_b2[(kd-1024)*32 + f];
    unsigned ub = __float_as_uint(v);
    float res = v - __uint_as_float(ub & 0xFFFF0000u);
    VrT_hi[f*1056 + kd] = (unsigned short)(ub >> 16);
    VrT_lo[f*1056 + kd] = (unsigned short)(__float_as_uint(res) >> 16);
  }
}

__global__ void k_count(const int* __restrict__ dst, int* __restrict__ counts, int E){
  int i = blockIdx.x*blockDim.x + threadIdx.x;
  if (i < E) atomicAdd(&counts[dst[i]], 1);
}

// 3-stage parallel exclusive scan
__global__ void k_scanA(const int* __restrict__ counts, int* __restrict__ row_off,
                        int* __restrict__ part, int N){
  __shared__ int buf[256];
  int b = blockIdx.x, t = threadIdx.x, base = b*256;
  int v = (base + t < N) ? counts[base + t] : 0;
  buf[t] = v; __syncthreads();
  #pragma unroll
  for (int off = 1; off < 256; off <<= 1){
    int tmp = (t >= off) ? buf[t-off] : 0;
    __syncthreads();
    buf[t] += tmp;
    __syncthreads();
  }
  if (base + t < N) row_off[base + t] = buf[t] - v;
  if (t == 255) part[b] = buf[255];
}

__global__ void k_scanB(int* __restrict__ part, int* __restrict__ row_off,
                        int nch, int N){
  __shared__ int buf[256];
  int t = threadIdx.x;
  int v = (t < nch) ? part[t] : 0;
  buf[t] = v; __syncthreads();
  #pragma unroll
  for (int off = 1; off < 256; off <<= 1){
    int tmp = (t >= off) ? buf[t-off] : 0;
    __syncthreads();
    buf[t] += tmp;
    __syncthreads();
  }
  if (t < nch) part[t] = buf[t] - v;
  if (t == 255) row_off[N] = buf[255];
}

__global__ void k_scanC(int* __restrict__ row_off, const int* __restrict__ part, int N){
  int i = blockIdx.x*256 + threadIdx.x;
  if (i < N) row_off[i] += part[blockIdx.x];
}

__global__ void k_scatter(const int* __restrict__ dst, const int* __restrict__ row_off,
                          int* __restrict__ cursor, int* __restrict__ eid, int E){
  int i = blockIdx.x*blockDim.x + threadIdx.x;
  if (i < E){
    int dn = dst[i];
    int pos = row_off[dn] + atomicAdd(&cursor[dn], 1);
    eid[pos] = i;
  }
}

// fused: hidq[p] = packsplit(relu(ea[eid[p]] @ e_w1 + e_b1)), srcp[p] = src[eid[p]]
__global__ void k_edgeCSR(const int* __restrict__ eid, const int* __restrict__ src,
                          const float* __restrict__ ea, const float* __restrict__ w,
                          const float* __restrict__ b, unsigned* __restrict__ hidq,
                          int* __restrict__ srcp, int E){
  int i = blockIdx.x*blockDim.x + threadIdx.x;
  if (i >= E*32) return;
  int p = i>>5, d = i&31;
  int e = eid[p];
  const float4* ea4 = (const float4*)ea;
  float4 v = ea4[e];
  float acc = b[d];
  acc = fmaf(v.x, w[0*32+d], acc);
  acc = fmaf(v.y, w[1*32+d], acc);
  acc = fmaf(v.z, w[2*32+d], acc);
  acc = fmaf(v.w, w[3*32+d], acc);
  hidq[i] = packsplit(fmaxf(acc, 0.f));
  if (d == 0) srcp[p] = src[e];
}

// Fused per-iteration kernel: 512 threads, 16 nodes (2 per wave in phase 1).
// phase 1: S[n] = H_e^T @ O_e via mfma_32x32x16_bf16 (x3 split), 16-edge chunks
// phase 2: aggr = S @ Vr via mfma_16x16x32_bf16 (x3), full M=16, 33 K-steps / 8 waves
// epilogue: reduce partials, root+relu, GRU.
__global__ __launch_bounds__(512) void k_iter(
    const int* __restrict__ row_off, const int* __restrict__ srcp,
    const unsigned* __restrict__ hidq, const float* __restrict__ cur_in,
    const unsigned short* __restrict__ VrT_hi, const unsigned short* __restrict__ VrT_lo,
    const float* __restrict__ root_w, const float* __restrict__ conv_b,
    const float* __restrict__ wih, const float* __restrict__ whh,
    const float* __restrict__ bih, const float* __restrict__ bhh,
    float* __restrict__ cur_out, int N){
  __shared__ __align__(16) unsigned s_lds[16*S_PAD];  // packed split-bf16 S rows
  __shared__ float htile[16*32];
  __shared__ float mtile[16*32];
  int nb = blockIdx.x*16;
  int t = threadIdx.x;
  int w = t >> 6, l = t & 63, col = l & 31, half = l >> 5;

  // stage htile early — overlaps phase 1
  {
    int node = t >> 5, f = t & 31;
    int n2 = nb + node;
    htile[t] = (n2 < N) ? cur_in[n2*32 + f] : 0.f;
  }

  // ---- phase 1: 2 nodes per wave, MFMA outer-product accumulation ----
  for (int q = 0; q < 2; ++q){
    int n = nb + w*2 + q;
    f32x16 Sacc = {0.f,0.f,0.f,0.f,0.f,0.f,0.f,0.f,
                   0.f,0.f,0.f,0.f,0.f,0.f,0.f,0.f};
    float aexp = 0.f;
    int lo = 0, hi = 0;
    if (n < N){ lo = row_off[n]; hi = row_off[n+1]; }
    for (int p0 = lo; p0 < hi; p0 += 16){
      short8 Ah, Al, Bh, Bl;
      #pragma unroll
      for (int j=0;j<8;++j){
        int pp = p0 + 8*half + j;
        bool val = pp < hi;
        int idx = val ? pp : lo;
        unsigned hp = hidq[idx*32 + col];         // A[k=col][edge] packed
        int s = srcp[idx];
        float ov = cur_in[s*32 + col];            // B[edge][d=col]
        ov = val ? ov : 0.f;
        Ah[j] = (short)(hp >> 16);
        Al[j] = (short)(hp & 0xffffu);
        unsigned uo = __float_as_uint(ov);
        float ores = ov - __uint_as_float(uo & 0xFFFF0000u);
        Bh[j] = (short)(uo >> 16);
        Bl[j] = (short)(__float_as_uint(ores) >> 16);
        aexp += ov;
      }
      Sacc = __builtin_amdgcn_mfma_f32_32x32x16_bf16(Ah, Bh, Sacc, 0,0,0);
      Sacc = __builtin_amdgcn_mfma_f32_32x32x16_bf16(Al, Bh, Sacc, 0,0,0);
      Sacc = __builtin_amdgcn_mfma_f32_32x32x16_bf16(Ah, Bl, Sacc, 0,0,0);
    }
    // write packed split S row: C row=(i&3)+8*(i>>2)+4*half (k), col=d
    unsigned* sp = &s_lds[(w*2+q)*S_PAD];
    #pragma unroll
    for (int i=0;i<16;++i){
      int k = (i&3) + 8*(i>>2) + 4*half;
      sp[k*32 + col] = packsplit(Sacc[i]);
    }
    aexp += __shfl_xor(aexp, 32, 64);
    if (l < 32) sp[1024 + l] = packsplit(aexp);
  }
  __syncthreads();

  // ---- phase 2: C[m][f] = sum_kd S[m][kd]*Vr[kd][f], 33 K-steps / 8 waves ----
  int fc = l & 15, hq = l >> 4;
  const unsigned* arow = &s_lds[fc*S_PAD];
  const unsigned short* bh0p = VrT_hi + fc*1056;
  const unsigned short* bl0p = VrT_lo + fc*1056;
  const unsigned short* bh1p = VrT_hi + (16+fc)*1056;
  const unsigned short* bl1p = VrT_lo + (16+fc)*1056;
  f32x4 acc0 = {0.f,0.f,0.f,0.f}, acc1 = {0.f,0.f,0.f,0.f};
  int s_lo = (w*33) >> 3, s_hi = ((w+1)*33) >> 3;
  for (int st = s_lo; st < s_hi; ++st){
    int kb = st*32 + hq*8;
    const uint4* ap = (const uint4*)(arow + kb);
    uint4 ua = ap[0], ub = ap[1];
    short8 Ah, Al;
    Ah[0]=(short)(ua.x>>16); Al[0]=(short)(ua.x & 0xffffu);
    Ah[1]=(short)(ua.y>>16); Al[1]=(short)(ua.y & 0xffffu);
    Ah[2]=(short)(ua.z>>16); Al[2]=(short)(ua.z & 0xffffu);
    Ah[3]=(short)(ua.w>>16); Al[3]=(short)(ua.w & 0xffffu);
    Ah[4]=(short)(ub.x>>16); Al[4]=(short)(ub.x & 0xffffu);
    Ah[5]=(short)(ub.y>>16); Al[5]=(short)(ub.y & 0xffffu);
    Ah[6]=(short)(ub.z>>16); Al[6]=(short)(ub.z & 0xffffu);
    Ah[7]=(short)(ub.w>>16); Al[7]=(short)(ub.w & 0xffffu);
    short8 bh0 = *(const short8*)(bh0p + kb);
    short8 bl0 = *(const short8*)(bl0p + kb);
    short8 bh1 = *(const short8*)(bh1p + kb);
    short8 bl1 = *(const short8*)(bl1p + kb);
    acc0 = __builtin_amdgcn_mfma_f32_16x16x32_bf16(Ah, bh0, acc0, 0,0,0);
    acc0 = __builtin_amdgcn_mfma_f32_16x16x32_bf16(Al, bh0, acc0, 0,0,0);
    acc0 = __builtin_amdgcn_mfma_f32_16x16x32_bf16(Ah, bl0, acc0, 0,0,0);
    acc1 = __builtin_amdgcn_mfma_f32_16x16x32_bf16(Ah, bh1, acc1, 0,0,0);
    acc1 = __builtin_amdgcn_mfma_f32_16x16x32_bf16(Al, bh1, acc1, 0,0,0);
    acc1 = __builtin_amdgcn_mfma_f32_16x16x32_bf16(Ah, bl1, acc1, 0,0,0);
  }
  __syncthreads();                       // all s_lds reads done
  float* pbuf = (float*)s_lds;           // reuse: [w][m(16)][32]
  #pragma unroll
  for (int i=0;i<4;++i){
    int m = hq*4 + i;                    // C row = node (all 16 valid)
    pbuf[(w*16 + m)*32 + fc]      = acc0[i];
    pbuf[(w*16 + m)*32 + 16 + fc] = acc1[i];
  }
  __syncthreads();

  // ---- epilogue: reduce partials, root+relu -> m, then GRU ----
  int node = t >> 5, f = t & 31;
  int n2 = nb + node;
  if (n2 < N){
    float msum = 0.f;
    #pragma unroll
    for (int w2=0; w2<8; ++w2) msum += pbuf[(w2*16 + node)*32 + f];
    float deg = (float)max(row_off[n2+1] - row_off[n2], 1);
    float rt = 0.f;
    #pragma unroll
    for (int k=0;k<32;++k) rt = fmaf(htile[node*32+k], root_w[k*32+f], rt);
    mtile[node*32 + f] = fmaxf(msum/deg + rt + conv_b[f], 0.f);
  }
  __syncthreads();
  if (n2 < N){
    float gr = bih[f], gz = bih[32+f], gn = bih[64+f];
    float hr = bhh[f], hz = bhh[32+f], hn = bhh[64+f];
    const float* mm = &mtile[node*32];
    const float* hh = &htile[node*32];
    #pragma unroll
    for (int k=0;k<32;++k){
      float mv = mm[k], hv = hh[k];
      gr = fmaf(mv, wih[k*96 + f],      gr);
      gz = fmaf(mv, wih[k*96 + 32 + f], gz);
      gn = fmaf(mv, wih[k*96 + 64 + f], gn);
      hr = fmaf(hv, whh[k*96 + f],      hr);
      hz = fmaf(hv, whh[k*96 + 32 + f], hz);
      hn = fmaf(hv, whh[k*96 + 64 + f], hn);
    }
    float r = sigf(gr + hr);
    float z = sigf(gz + hz);
    float nn2 = tanhf(gn + r*hn);
    cur_out[n2*32 + f] = (1.f - z)*nn2 + z*hh[f];
  }
}

// Set2Set x6 + memory LSTM + FC head; ONE WAVE per graph (wave-synchronous,
// single-wave __syncthreads ~ free; all reductions via shfl; cs in registers).
#define S2S_CAP 480
__global__ __launch_bounds__(64) void k_s2s(
    const float* __restrict__ cur,
    const float* __restrict__ wi, const float* __restrict__ wh, const float* __restrict__ sb,
    const float* __restrict__ mwi, const float* __restrict__ mwh, const float* __restrict__ mb,
    const float* __restrict__ hx, const float* __restrict__ cx,
    const float* __restrict__ f1w, const float* __restrict__ f1b,
    const float* __restrict__ f2w, const float* __restrict__ f2b,
    float* __restrict__ out, int N, int G){
  int g = blockIdx.x, l = threadIdx.x;
  int lo = (int)(((long long)g*N + G - 1)/G);
  int hi = (int)(((long long)(g+1)*N + G - 1)/G);
  int cnt = hi - lo;                     // <= S2S_CAP (469 at N=15000,G=32)
  __shared__ float curL[S2S_CAP*33];
  __shared__ float ebuf[S2S_CAP];
  __shared__ float qstar[64], hsS[32], gbuf[128];
  __shared__ float hnew[32], f1o[32];
  // stage cur slice: 8 rows per pass, float4 per lane
  {
    int c4 = (l & 7)*4;
    for (int r = l >> 3; r < cnt; r += 8){
      float4 v = *(const float4*)&cur[(size_t)(lo + r)*32 + c4];
      float* dstp = &curL[r*33 + c4];
      dstp[0] = v.x; dstp[1] = v.y; dstp[2] = v.z; dstp[3] = v.w;
    }
  }
  if (l < 64) qstar[l] = 0.f;
  if (l < 32) hsS[l] = 0.f;
  float cs = 0.f;                        // lanes 0..31 own cell state
  int d = l & 31, halfw = l >> 5;
  __syncthreads();
  for (int it = 0; it < 6; ++it){
    // gbuf[o] for o=l and o=64+l
    {
      float a0 = sb[l], a1 = sb[64 + l];
      #pragma unroll 8
      for (int j=0;j<64;++j){
        float qv = qstar[j];
        a0 = fmaf(qv, wi[j*128 + l], a0);
        a1 = fmaf(qv, wi[j*128 + 64 + l], a1);
      }
      #pragma unroll 8
      for (int j=0;j<32;++j){
        float hv = hsS[j];
        a0 = fmaf(hv, wh[j*128 + l], a0);
        a1 = fmaf(hv, wh[j*128 + 64 + l], a1);
      }
      gbuf[l] = a0; gbuf[64 + l] = a1;
    }
    __syncthreads();
    if (l < 32){
      float c = sigf(gbuf[32+l])*cs + sigf(gbuf[l])*tanhf(gbuf[64+l]);
      cs = c;
      hsS[l] = sigf(gbuf[96+l])*tanhf(c);
    }
    __syncthreads();
    // pass 1: e[p] = <curL[p], q>, wave max
    float lmax = -3.4e38f;
    for (int p = l; p < cnt; p += 64){
      float acc = 0.f;
      #pragma unroll
      for (int d2=0; d2<32; ++d2) acc = fmaf(curL[p*33 + d2], hsS[d2], acc);
      ebuf[p] = acc;
      lmax = fmaxf(lmax, acc);
    }
    #pragma unroll
    for (int o2 = 1; o2 < 64; o2 <<= 1) lmax = fmaxf(lmax, __shfl_xor(lmax, o2, 64));
    float bmax = lmax;
    // pass 2: a = exp(e-max) on own entries (no cross-lane yet), wave sum
    float lsum = 0.f;
    for (int p = l; p < cnt; p += 64){
      float a = expf(ebuf[p] - bmax);
      ebuf[p] = a;
      lsum += a;
    }
    #pragma unroll
    for (int o2 = 1; o2 < 64; o2 <<= 1) lsum += __shfl_xor(lsum, o2, 64);
    float bsum = lsum;
    __syncthreads();                     // all ebuf visible
    // r[d] = sum_p a[p]*curL[p][d]; lane owns (d, half), p ≡ half (mod 2)
    float r0 = 0.f, r1 = 0.f;
    for (int p = halfw; p < cnt; p += 4){
      r0 = fmaf(ebuf[p], curL[p*33 + d], r0);
      int p2 = p + 2;
      if (p2 < cnt) r1 = fmaf(ebuf[p2], curL[p2*33 + d], r1);
    }
    float racc = r0 + r1;
    racc += __shfl_xor(racc, 32, 64);
    __syncthreads();
    if (l < 32){
      qstar[l] = hsS[l];
      qstar[32 + l] = racc / bsum;
    }
    __syncthreads();
  }
  // memory LSTM + FC head
  {
    float a0 = mb[l], a1 = mb[64 + l];
    #pragma unroll 8
    for (int j=0;j<64;++j){
      float qv = qstar[j];
      a0 = fmaf(qv, mwi[j*128 + l], a0);
      a1 = fmaf(qv, mwi[j*128 + 64 + l], a1);
    }
    #pragma unroll 8
    for (int j=0;j<32;++j){
      float hv = hx[g*32 + j];
      a0 = fmaf(hv, mwh[j*128 + l], a0);
      a1 = fmaf(hv, mwh[j*128 + 64 + l], a1);
    }
    gbuf[l] = a0; gbuf[64 + l] = a1;
  }
  __syncthreads();
  if (l < 32){
    float c = sigf(gbuf[32+l])*cx[g*32+l] + sigf(gbuf[l])*tanhf(gbuf[64+l]);
    float h = sigf(gbuf[96+l])*tanhf(c);
    out[G + g*32 + l] = h;
    out[G + G*32 + g*32 + l] = c;
    hnew[l] = h;
  }
  __syncthreads();
  if (l < 32){
    float acc = f1b[l];
    #pragma unroll
    for (int k=0;k<32;++k) acc = fmaf(hnew[k], f1w[k*32+l], acc);
    f1o[l] = fmaxf(acc, 0.f);
  }
  __syncthreads();
  float pv = (l < 32) ? f1o[l]*f2w[l] : 0.f;
  #pragma unroll
  for (int o2 = 1; o2 < 32; o2 <<= 1) pv += __shfl_xor(pv, o2, 64);
  if (l == 0) out[g] = pv + f2b[0];
}

extern "C" void kernel_launch(void* const* d_in, const int* in_sizes, int n_in,
                              void* d_out, int out_size, void* d_ws, size_t ws_size,
                              hipStream_t stream) {
  const float* x      = (const float*)d_in[0];
  const float* ea     = (const float*)d_in[1];
  const float* hx     = (const float*)d_in[2];
  const float* cx     = (const float*)d_in[3];
  const float* lin0_w = (const float*)d_in[4];
  const float* lin0_b = (const float*)d_in[5];
  const float* e_w1   = (const float*)d_in[6];
  const float* e_b1   = (const float*)d_in[7];
  const float* e_w2   = (const float*)d_in[8];
  const float* e_b2   = (const float*)d_in[9];
  const float* root_w = (const float*)d_in[10];
  const float* conv_b = (const float*)d_in[11];
  const float* g_wih  = (const float*)d_in[12];
  const float* g_whh  = (const float*)d_in[13];
  const float* g_bih  = (const float*)d_in[14];
  const float* g_bhh  = (const float*)d_in[15];
  const float* s_wi   = (const float*)d_in[16];
  const float* s_wh   = (const float*)d_in[17];
  const float* s_b    = (const float*)d_in[18];
  const float* m_wi   = (const float*)d_in[19];
  const float* m_wh   = (const float*)d_in[20];
  const float* m_b    = (const float*)d_in[21];
  const float* f1w    = (const float*)d_in[22];
  const float* f1b    = (const float*)d_in[23];
  const float* f2w    = (const float*)d_in[24];
  const float* f2b    = (const float*)d_in[25];
  const int*   eidx   = (const int*)d_in[26];
  int N = in_sizes[0]/3;
  int E = in_sizes[1]/4;
  int G = in_sizes[2]/32;
  const int* srcI = eidx;
  const int* dstI = eidx + E;
  float* outF = (float*)d_out;

  char* wbase = (char*)d_ws; size_t off = 0;
  auto carve = [&](size_t nbytes)->char*{
    char* p = wbase + off; off = (off + nbytes + 255) & ~(size_t)255; return p;
  };
  float* cur0    = (float*)carve((size_t)N*32*4);
  float* cur1    = (float*)carve((size_t)N*32*4);
  unsigned* hidq = (unsigned*)carve((size_t)E*32*4);
  unsigned short* VrT_hi = (unsigned short*)carve((size_t)1056*32*2);
  unsigned short* VrT_lo = (unsigned short*)carve((size_t)1056*32*2);
  int*   counts  = (int*)carve((size_t)N*4);
  int*   cursor  = (int*)carve((size_t)N*4);
  int*   row_off = (int*)carve((size_t)(N+1)*4);
  int*   eid     = (int*)carve((size_t)E*4);
  int*   srcp    = (int*)carve((size_t)E*4);
  int*   part    = (int*)carve((size_t)256*4);
  (void)ws_size; (void)n_in; (void)out_size;

  int nch = (N + 255)/256;

  // phase A: fused pre (init+lin0+W2 split), CSR build with parallel scan
  k_pre<<<(N*32+255)/256, 256, 0, stream>>>(x, lin0_w, lin0_b, e_w2, e_b2,
                                            cur0, VrT_hi, VrT_lo, counts, cursor, N);
  k_count<<<(E+255)/256, 256, 0, stream>>>(dstI, counts, E);
  k_scanA<<<nch, 256, 0, stream>>>(counts, row_off, part, N);
  k_scanB<<<1, 256, 0, stream>>>(part, row_off, nch, N);
  k_scanC<<<nch, 256, 0, stream>>>(row_off, part, N);
  k_scatter<<<(E+255)/256, 256, 0, stream>>>(dstI, row_off, cursor, eid, E);
  k_edgeCSR<<<(E*32+255)/256, 256, 0, stream>>>(eid, srcI, ea, e_w1, e_b1, hidq, srcp, E);

  // phase B: 6 fused message-passing + GRU iterations (ping-pong cur)
  float* cin = cur0; float* cout = cur1;
  for (int it = 0; it < 6; ++it){
    k_iter<<<(N+15)/16, 512, 0, stream>>>(row_off, srcp, hidq, cin, VrT_hi, VrT_lo,
                                          root_w, conv_b, g_wih, g_whh, g_bih, g_bhh,
                                          cout, N);
    float* tmp = cin; cin = cout; cout = tmp;
  }

  // phase C+D: Set2Set x6 + memory LSTM + FC head (one wave per graph)
  k_s2s<<<G, 64, 0, stream>>>(cin, s_wi, s_wh, s_b, m_wi, m_wh, m_b,
                              hx, cx, f1w, f1b, f2w, f2b, outF, N, G);
}

// Round 7
// 332.503 us; speedup vs baseline: 3.1888x; 1.2059x over previous
//
#include <hip/hip_runtime.h>
#include <math.h>

// CriticBatchNet: NNConv(+edge-net) + GRU x6, Set2Set x6, LSTM head.
// msg[e] = out[src]@W_e[e], W_e[e]=hidden[e]@e_w2+b2
//   => segsum_dst(msg)[m,f] = sum_kd S[m,kd]*Vr[kd,f],
//      S[m,k*32+d] = sum_{e:dst=m} hidden[e,k]*out[src_e,d]
//      S[m,1024+j] = sum_{e:dst=m} out[src_e,j]   (bias rows)
// v7: k_s2s back to 512 threads (8-wave TLP, r5 structure) + s2s LSTM
//     weights staged in LDS once (no global reads in the iteration loop);
//     gate matvec j-split 4-way across 512 threads. k_iter unchanged (v6).

typedef __attribute__((ext_vector_type(8))) short short8;
typedef __attribute__((ext_vector_type(4))) float f32x4;
typedef __attribute__((ext_vector_type(16))) float f32x16;

#define S_PAD 1060

__device__ __forceinline__ float sigf(float x){ return 1.f/(1.f+expf(-x)); }

__device__ __forceinline__ unsigned packsplit(float v){
  unsigned uv = __float_as_uint(v);
  float res = v - __uint_as_float(uv & 0xFFFF0000u);
  return (uv & 0xFFFF0000u) | (__float_as_uint(res) >> 16);
}

// fused: zero counts/cursor, lin0, permW2split
__global__ void k_pre(const float* __restrict__ x, const float* __restrict__ w,
                      const float* __restrict__ b,
                      const float* __restrict__ e_w2, const float* __restrict__ e_b2,
                      float* __restrict__ cur, unsigned short* __restrict__ VrT_hi,
                      unsigned short* __restrict__ VrT_lo,
                      int* __restrict__ counts, int* __restrict__ cursor, int N){
  int i = blockIdx.x*blockDim.x + threadIdx.x;
  if (i < N){ counts[i]=0; cursor[i]=0; }
  if (i < N*32){
    int n = i>>5, d = i&31;
    float acc = b[d];
    acc = fmaf(x[n*3+0], w[0*32+d], acc);
    acc = fmaf(x[n*3+1], w[1*32+d], acc);
    acc = fmaf(x[n*3+2], w[2*32+d], acc);
    cur[i] = fmaxf(acc, 0.f);
  }
  if (i < 1056*32){
    int f = i & 31, kd = i >> 5;
    float v = (kd < 1024) ? e_w2[(kd>>5)*1024 + (kd&31)*32 + f]
                          : e_b2[(kd-1024)*32 + f];
    unsigned ub = __float_as_uint(v);
    float res = v - __uint_as_float(ub & 0xFFFF0000u);
    VrT_hi[f*1056 + kd] = (unsigned short)(ub >> 16);
    VrT_lo[f*1056 + kd] = (unsigned short)(__float_as_uint(res) >> 16);
  }
}

__global__ void k_count(const int* __restrict__ dst, int* __restrict__ counts, int E){
  int i = blockIdx.x*blockDim.x + threadIdx.x;
  if (i < E) atomicAdd(&counts[dst[i]], 1);
}

// 3-stage parallel exclusive scan
__global__ void k_scanA(const int* __restrict__ counts, int* __restrict__ row_off,
                        int* __restrict__ part, int N){
  __shared__ int buf[256];
  int b = blockIdx.x, t = threadIdx.x, base = b*256;
  int v = (base + t < N) ? counts[base + t] : 0;
  buf[t] = v; __syncthreads();
  #pragma unroll
  for (int off = 1; off < 256; off <<= 1){
    int tmp = (t >= off) ? buf[t-off] : 0;
    __syncthreads();
    buf[t] += tmp;
    __syncthreads();
  }
  if (base + t < N) row_off[base + t] = buf[t] - v;
  if (t == 255) part[b] = buf[255];
}

__global__ void k_scanB(int* __restrict__ part, int* __restrict__ row_off,
                        int nch, int N){
  __shared__ int buf[256];
  int t = threadIdx.x;
  int v = (t < nch) ? part[t] : 0;
  buf[t] = v; __syncthreads();
  #pragma unroll
  for (int off = 1; off < 256; off <<= 1){
    int tmp = (t >= off) ? buf[t-off] : 0;
    __syncthreads();
    buf[t] += tmp;
    __syncthreads();
  }
  if (t < nch) part[t] = buf[t] - v;
  if (t == 255) row_off[N] = buf[255];
}

__global__ void k_scanC(int* __restrict__ row_off, const int* __restrict__ part, int N){
  int i = blockIdx.x*256 + threadIdx.x;
  if (i < N) row_off[i] += part[blockIdx.x];
}

__global__ void k_scatter(const int* __restrict__ dst, const int* __restrict__ row_off,
                          int* __restrict__ cursor, int* __restrict__ eid, int E){
  int i = blockIdx.x*blockDim.x + threadIdx.x;
  if (i < E){
    int dn = dst[i];
    int pos = row_off[dn] + atomicAdd(&cursor[dn], 1);
    eid[pos] = i;
  }
}

// fused: hidq[p] = packsplit(relu(ea[eid[p]] @ e_w1 + e_b1)), srcp[p] = src[eid[p]]
__global__ void k_edgeCSR(const int* __restrict__ eid, const int* __restrict__ src,
                          const float* __restrict__ ea, const float* __restrict__ w,
                          const float* __restrict__ b, unsigned* __restrict__ hidq,
                          int* __restrict__ srcp, int E){
  int i = blockIdx.x*blockDim.x + threadIdx.x;
  if (i >= E*32) return;
  int p = i>>5, d = i&31;
  int e = eid[p];
  const float4* ea4 = (const float4*)ea;
  float4 v = ea4[e];
  float acc = b[d];
  acc = fmaf(v.x, w[0*32+d], acc);
  acc = fmaf(v.y, w[1*32+d], acc);
  acc = fmaf(v.z, w[2*32+d], acc);
  acc = fmaf(v.w, w[3*32+d], acc);
  hidq[i] = packsplit(fmaxf(acc, 0.f));
  if (d == 0) srcp[p] = src[e];
}

// Fused per-iteration kernel: 512 threads, 16 nodes (2 per wave in phase 1).
__global__ __launch_bounds__(512) void k_iter(
    const int* __restrict__ row_off, const int* __restrict__ srcp,
    const unsigned* __restrict__ hidq, const float* __restrict__ cur_in,
    const unsigned short* __restrict__ VrT_hi, const unsigned short* __restrict__ VrT_lo,
    const float* __restrict__ root_w, const float* __restrict__ conv_b,
    const float* __restrict__ wih, const float* __restrict__ whh,
    const float* __restrict__ bih, const float* __restrict__ bhh,
    float* __restrict__ cur_out, int N){
  __shared__ __align__(16) unsigned s_lds[16*S_PAD];  // packed split-bf16 S rows
  __shared__ float htile[16*32];
  __shared__ float mtile[16*32];
  int nb = blockIdx.x*16;
  int t = threadIdx.x;
  int w = t >> 6, l = t & 63, col = l & 31, half = l >> 5;

  // stage htile early — overlaps phase 1
  {
    int node = t >> 5, f = t & 31;
    int n2 = nb + node;
    htile[t] = (n2 < N) ? cur_in[n2*32 + f] : 0.f;
  }

  // ---- phase 1: 2 nodes per wave, MFMA outer-product accumulation ----
  for (int q = 0; q < 2; ++q){
    int n = nb + w*2 + q;
    f32x16 Sacc = {0.f,0.f,0.f,0.f,0.f,0.f,0.f,0.f,
                   0.f,0.f,0.f,0.f,0.f,0.f,0.f,0.f};
    float aexp = 0.f;
    int lo = 0, hi = 0;
    if (n < N){ lo = row_off[n]; hi = row_off[n+1]; }
    for (int p0 = lo; p0 < hi; p0 += 16){
      short8 Ah, Al, Bh, Bl;
      #pragma unroll
      for (int j=0;j<8;++j){
        int pp = p0 + 8*half + j;
        bool val = pp < hi;
        int idx = val ? pp : lo;
        unsigned hp = hidq[idx*32 + col];         // A[k=col][edge] packed
        int s = srcp[idx];
        float ov = cur_in[s*32 + col];            // B[edge][d=col]
        ov = val ? ov : 0.f;
        Ah[j] = (short)(hp >> 16);
        Al[j] = (short)(hp & 0xffffu);
        unsigned uo = __float_as_uint(ov);
        float ores = ov - __uint_as_float(uo & 0xFFFF0000u);
        Bh[j] = (short)(uo >> 16);
        Bl[j] = (short)(__float_as_uint(ores) >> 16);
        aexp += ov;
      }
      Sacc = __builtin_amdgcn_mfma_f32_32x32x16_bf16(Ah, Bh, Sacc, 0,0,0);
      Sacc = __builtin_amdgcn_mfma_f32_32x32x16_bf16(Al, Bh, Sacc, 0,0,0);
      Sacc = __builtin_amdgcn_mfma_f32_32x32x16_bf16(Ah, Bl, Sacc, 0,0,0);
    }
    // write packed split S row: C row=(i&3)+8*(i>>2)+4*half (k), col=d
    unsigned* sp = &s_lds[(w*2+q)*S_PAD];
    #pragma unroll
    for (int i=0;i<16;++i){
      int k = (i&3) + 8*(i>>2) + 4*half;
      sp[k*32 + col] = packsplit(Sacc[i]);
    }
    aexp += __shfl_xor(aexp, 32, 64);
    if (l < 32) sp[1024 + l] = packsplit(aexp);
  }
  __syncthreads();

  // ---- phase 2: C[m][f] = sum_kd S[m][kd]*Vr[kd][f], 33 K-steps / 8 waves ----
  int fc = l & 15, hq = l >> 4;
  const unsigned* arow = &s_lds[fc*S_PAD];
  const unsigned short* bh0p = VrT_hi + fc*1056;
  const unsigned short* bl0p = VrT_lo + fc*1056;
  const unsigned short* bh1p = VrT_hi + (16+fc)*1056;
  const unsigned short* bl1p = VrT_lo + (16+fc)*1056;
  f32x4 acc0 = {0.f,0.f,0.f,0.f}, acc1 = {0.f,0.f,0.f,0.f};
  int s_lo = (w*33) >> 3, s_hi = ((w+1)*33) >> 3;
  for (int st = s_lo; st < s_hi; ++st){
    int kb = st*32 + hq*8;
    const uint4* ap = (const uint4*)(arow + kb);
    uint4 ua = ap[0], ub = ap[1];
    short8 Ah, Al;
    Ah[0]=(short)(ua.x>>16); Al[0]=(short)(ua.x & 0xffffu);
    Ah[1]=(short)(ua.y>>16); Al[1]=(short)(ua.y & 0xffffu);
    Ah[2]=(short)(ua.z>>16); Al[2]=(short)(ua.z & 0xffffu);
    Ah[3]=(short)(ua.w>>16); Al[3]=(short)(ua.w & 0xffffu);
    Ah[4]=(short)(ub.x>>16); Al[4]=(short)(ub.x & 0xffffu);
    Ah[5]=(short)(ub.y>>16); Al[5]=(short)(ub.y & 0xffffu);
    Ah[6]=(short)(ub.z>>16); Al[6]=(short)(ub.z & 0xffffu);
    Ah[7]=(short)(ub.w>>16); Al[7]=(short)(ub.w & 0xffffu);
    short8 bh0 = *(const short8*)(bh0p + kb);
    short8 bl0 = *(const short8*)(bl0p + kb);
    short8 bh1 = *(const short8*)(bh1p + kb);
    short8 bl1 = *(const short8*)(bl1p + kb);
    acc0 = __builtin_amdgcn_mfma_f32_16x16x32_bf16(Ah, bh0, acc0, 0,0,0);
    acc0 = __builtin_amdgcn_mfma_f32_16x16x32_bf16(Al, bh0, acc0, 0,0,0);
    acc0 = __builtin_amdgcn_mfma_f32_16x16x32_bf16(Ah, bl0, acc0, 0,0,0);
    acc1 = __builtin_amdgcn_mfma_f32_16x16x32_bf16(Ah, bh1, acc1, 0,0,0);
    acc1 = __builtin_amdgcn_mfma_f32_16x16x32_bf16(Al, bh1, acc1, 0,0,0);
    acc1 = __builtin_amdgcn_mfma_f32_16x16x32_bf16(Ah, bl1, acc1, 0,0,0);
  }
  __syncthreads();                       // all s_lds reads done
  float* pbuf = (float*)s_lds;           // reuse: [w][m(16)][32]
  #pragma unroll
  for (int i=0;i<4;++i){
    int m = hq*4 + i;                    // C row = node (all 16 valid)
    pbuf[(w*16 + m)*32 + fc]      = acc0[i];
    pbuf[(w*16 + m)*32 + 16 + fc] = acc1[i];
  }
  __syncthreads();

  // ---- epilogue: reduce partials, root+relu -> m, then GRU ----
  int node = t >> 5, f = t & 31;
  int n2 = nb + node;
  if (n2 < N){
    float msum = 0.f;
    #pragma unroll
    for (int w2=0; w2<8; ++w2) msum += pbuf[(w2*16 + node)*32 + f];
    float deg = (float)max(row_off[n2+1] - row_off[n2], 1);
    float rt = 0.f;
    #pragma unroll
    for (int k=0;k<32;++k) rt = fmaf(htile[node*32+k], root_w[k*32+f], rt);
    mtile[node*32 + f] = fmaxf(msum/deg + rt + conv_b[f], 0.f);
  }
  __syncthreads();
  if (n2 < N){
    float gr = bih[f], gz = bih[32+f], gn = bih[64+f];
    float hr = bhh[f], hz = bhh[32+f], hn = bhh[64+f];
    const float* mm = &mtile[node*32];
    const float* hh = &htile[node*32];
    #pragma unroll
    for (int k=0;k<32;++k){
      float mv = mm[k], hv = hh[k];
      gr = fmaf(mv, wih[k*96 + f],      gr);
      gz = fmaf(mv, wih[k*96 + 32 + f], gz);
      gn = fmaf(mv, wih[k*96 + 64 + f], gn);
      hr = fmaf(hv, whh[k*96 + f],      hr);
      hz = fmaf(hv, whh[k*96 + 32 + f], hz);
      hn = fmaf(hv, whh[k*96 + 64 + f], hn);
    }
    float r = sigf(gr + hr);
    float z = sigf(gz + hz);
    float nn2 = tanhf(gn + r*hn);
    cur_out[n2*32 + f] = (1.f - z)*nn2 + z*hh[f];
  }
}

// Set2Set x6 + memory LSTM + FC head; one 512-thread block per graph.
// All per-iteration operands (cur slice, LSTM weights) live in LDS.
#define S2S_CAP 480
__global__ __launch_bounds__(512) void k_s2s(
    const float* __restrict__ cur,
    const float* __restrict__ wi, const float* __restrict__ wh, const float* __restrict__ sb,
    const float* __restrict__ mwi, const float* __restrict__ mwh, const float* __restrict__ mb,
    const float* __restrict__ hx, const float* __restrict__ cx,
    const float* __restrict__ f1w, const float* __restrict__ f1b,
    const float* __restrict__ f2w, const float* __restrict__ f2b,
    float* __restrict__ out, int N, int G){
  int g = blockIdx.x, t = threadIdx.x;
  int lo = (int)(((long long)g*N + G - 1)/G);
  int hi = (int)(((long long)(g+1)*N + G - 1)/G);
  int cnt = hi - lo;                     // <= S2S_CAP (469 at N=15000,G=32)
  __shared__ float curL[S2S_CAP*33];     // 63.4 KB
  __shared__ float wiL[96*128];          // 49.2 KB: rows 0..63 = wi, 64..95 = wh
  __shared__ float ebuf[S2S_CAP];
  __shared__ float qh[96];               // [0..63]=q_star, [64..95]=hs
  __shared__ float csS[32];
  __shared__ float gbuf[128];
  __shared__ float pbuf4[4][128];
  __shared__ float redr[8*32];
  __shared__ float smax[8], ssum[8];
  __shared__ float bmaxS, bsumS;
  __shared__ float hnew[32], f1o[32];
  // stage cur slice + weights (coalesced)
  for (int i = t; i < cnt*32; i += 512){
    int p = i >> 5, d2 = i & 31;
    curL[p*33 + d2] = cur[(size_t)(lo + p)*32 + d2];
  }
  for (int i = t; i < 96*128; i += 512){
    int j = i >> 7, o = i & 127;
    wiL[i] = (j < 64) ? wi[j*128 + o] : wh[(j-64)*128 + o];
  }
  if (t < 96) qh[t] = 0.f;
  if (t < 32) csS[t] = 0.f;
  __syncthreads();
  int wv = t >> 6, l = t & 63, d = l & 31, halfw = l >> 5;
  int p0 = wv*2 + halfw;
  for (int it = 0; it < 6; ++it){
    // gates: o = t&127, j-split 4-way (24 each)
    {
      int o = t & 127, part = t >> 7;
      const float* wp = &wiL[part*24*128 + o];
      const float* qp = &qh[part*24];
      float a = 0.f;
      #pragma unroll
      for (int jj=0;jj<24;++jj) a = fmaf(qp[jj], wp[jj*128], a);
      pbuf4[part][o] = a;
    }
    __syncthreads();
    if (t < 128) gbuf[t] = pbuf4[0][t]+pbuf4[1][t]+pbuf4[2][t]+pbuf4[3][t] + sb[t];
    __syncthreads();
    if (t < 32){
      float c = sigf(gbuf[32+t])*csS[t] + sigf(gbuf[t])*tanhf(gbuf[64+t]);
      csS[t] = c;
      qh[64+t] = sigf(gbuf[96+t])*tanhf(c);   // hs (also q for the dots)
    }
    __syncthreads();
    // pass 1: e[p] = <curL[p], q>; thread-per-node
    float lmax = -3.4e38f;
    for (int p = t; p < cnt; p += 512){
      float acc = 0.f;
      #pragma unroll
      for (int d2=0; d2<32; ++d2) acc = fmaf(curL[p*33 + d2], qh[64+d2], acc);
      ebuf[p] = acc;
      lmax = fmaxf(lmax, acc);
    }
    #pragma unroll
    for (int o2 = 1; o2 < 64; o2 <<= 1) lmax = fmaxf(lmax, __shfl_xor(lmax, o2, 64));
    if (l == 0) smax[wv] = lmax;
    __syncthreads();
    if (t == 0){ float mm = smax[0]; for (int i=1;i<8;++i) mm = fmaxf(mm, smax[i]); bmaxS = mm; }
    __syncthreads();
    float bmax = bmaxS;
    // pass 2: a = exp(e-max); block sum
    float lsum = 0.f;
    for (int p = t; p < cnt; p += 512){
      float a = expf(ebuf[p] - bmax);
      ebuf[p] = a;
      lsum += a;
    }
    #pragma unroll
    for (int o2 = 1; o2 < 64; o2 <<= 1) lsum += __shfl_xor(lsum, o2, 64);
    if (l == 0) ssum[wv] = lsum;
    __syncthreads();
    if (t == 0){ float s2 = 0.f; for (int i=0;i<8;++i) s2 += ssum[i]; bsumS = s2; }
    __syncthreads();
    // pass 3: r[d] = sum_p a[p]*curL[p][d]
    float racc = 0.f;
    for (int p = p0; p < cnt; p += 16)
      racc = fmaf(ebuf[p], curL[p*33 + d], racc);
    racc += __shfl_xor(racc, 32, 64);
    if (l < 32) redr[wv*32 + l] = racc;
    __syncthreads();
    if (t < 32){
      float rsum = 0.f;
      #pragma unroll
      for (int w2=0; w2<8; ++w2) rsum += redr[w2*32 + t];
      qh[t] = qh[64+t];                 // q_star[:32] = q
      qh[32 + t] = rsum / bsumS;        // q_star[32:] = r_
    }
    __syncthreads();
  }
  // memory LSTM + FC head (runs once; global weight reads fine)
  if (t < 128){
    float acc = mb[t];
    for (int j=0;j<64;++j) acc = fmaf(qh[j], mwi[j*128+t], acc);
    for (int j=0;j<32;++j) acc = fmaf(hx[g*32+j], mwh[j*128+t], acc);
    gbuf[t] = acc;
  }
  __syncthreads();
  if (t < 32){
    float c = sigf(gbuf[32+t])*cx[g*32+t] + sigf(gbuf[t])*tanhf(gbuf[64+t]);
    float h = sigf(gbuf[96+t])*tanhf(c);
    out[G + g*32 + t] = h;
    out[G + G*32 + g*32 + t] = c;
    hnew[t] = h;
  }
  __syncthreads();
  if (t < 32){
    float acc = f1b[t];
    #pragma unroll
    for (int k=0;k<32;++k) acc = fmaf(hnew[k], f1w[k*32+t], acc);
    f1o[t] = fmaxf(acc, 0.f);
  }
  __syncthreads();
  if (t == 0){
    float acc = f2b[0];
    #pragma unroll
    for (int k=0;k<32;++k) acc = fmaf(f1o[k], f2w[k], acc);
    out[g] = acc;
  }
}

extern "C" void kernel_launch(void* const* d_in, const int* in_sizes, int n_in,
                              void* d_out, int out_size, void* d_ws, size_t ws_size,
                              hipStream_t stream) {
  const float* x      = (const float*)d_in[0];
  const float* ea     = (const float*)d_in[1];
  const float* hx     = (const float*)d_in[2];
  const float* cx     = (const float*)d_in[3];
  const float* lin0_w = (const float*)d_in[4];
  const float* lin0_b = (const float*)d_in[5];
  const float* e_w1   = (const float*)d_in[6];
  const float* e_b1   = (const float*)d_in[7];
  const float* e_w2   = (const float*)d_in[8];
  const float* e_b2   = (const float*)d_in[9];
  const float* root_w = (const float*)d_in[10];
  const float* conv_b = (const float*)d_in[11];
  const float* g_wih  = (const float*)d_in[12];
  const float* g_whh  = (const float*)d_in[13];
  const float* g_bih  = (const float*)d_in[14];
  const float* g_bhh  = (const float*)d_in[15];
  const float* s_wi   = (const float*)d_in[16];
  const float* s_wh   = (const float*)d_in[17];
  const float* s_b    = (const float*)d_in[18];
  const float* m_wi   = (const float*)d_in[19];
  const float* m_wh   = (const float*)d_in[20];
  const float* m_b    = (const float*)d_in[21];
  const float* f1w    = (const float*)d_in[22];
  const float* f1b    = (const float*)d_in[23];
  const float* f2w    = (const float*)d_in[24];
  const float* f2b    = (const float*)d_in[25];
  const int*   eidx   = (const int*)d_in[26];
  int N = in_sizes[0]/3;
  int E = in_sizes[1]/4;
  int G = in_sizes[2]/32;
  const int* srcI = eidx;
  const int* dstI = eidx + E;
  float* outF = (float*)d_out;

  char* wbase = (char*)d_ws; size_t off = 0;
  auto carve = [&](size_t nbytes)->char*{
    char* p = wbase + off; off = (off + nbytes + 255) & ~(size_t)255; return p;
  };
  float* cur0    = (float*)carve((size_t)N*32*4);
  float* cur1    = (float*)carve((size_t)N*32*4);
  unsigned* hidq = (unsigned*)carve((size_t)E*32*4);
  unsigned short* VrT_hi = (unsigned short*)carve((size_t)1056*32*2);
  unsigned short* VrT_lo = (unsigned short*)carve((size_t)1056*32*2);
  int*   counts  = (int*)carve((size_t)N*4);
  int*   cursor  = (int*)carve((size_t)N*4);
  int*   row_off = (int*)carve((size_t)(N+1)*4);
  int*   eid     = (int*)carve((size_t)E*4);
  int*   srcp    = (int*)carve((size_t)E*4);
  int*   part    = (int*)carve((size_t)256*4);
  (void)ws_size; (void)n_in; (void)out_size;

  int nch = (N + 255)/256;

  // phase A: fused pre (init+lin0+W2 split), CSR build with parallel scan
  k_pre<<<(N*32+255)/256, 256, 0, stream>>>(x, lin0_w, lin0_b, e_w2, e_b2,
                                            cur0, VrT_hi, VrT_lo, counts, cursor, N);
  k_count<<<(E+255)/256, 256, 0, stream>>>(dstI, counts, E);
  k_scanA<<<nch, 256, 0, stream>>>(counts, row_off, part, N);
  k_scanB<<<1, 256, 0, stream>>>(part, row_off, nch, N);
  k_scanC<<<nch, 256, 0, stream>>>(row_off, part, N);
  k_scatter<<<(E+255)/256, 256, 0, stream>>>(dstI, row_off, cursor, eid, E);
  k_edgeCSR<<<(E*32+255)/256, 256, 0, stream>>>(eid, srcI, ea, e_w1, e_b1, hidq, srcp, E);

  // phase B: 6 fused message-passing + GRU iterations (ping-pong cur)
  float* cin = cur0; float* cout = cur1;
  for (int it = 0; it < 6; ++it){
    k_iter<<<(N+15)/16, 512, 0, stream>>>(row_off, srcp, hidq, cin, VrT_hi, VrT_lo,
                                          root_w, conv_b, g_wih, g_whh, g_bih, g_bhh,
                                          cout, N);
    float* tmp = cin; cin = cout; cout = tmp;
  }

  // phase C+D: Set2Set x6 + memory LSTM + FC head
  k_s2s<<<G, 512, 0, stream>>>(cin, s_wi, s_wh, s_b, m_wi, m_wh, m_b,
                               hx, cx, f1w, f1b, f2w, f2b, outF, N, G);
}

// Round 8
// 312.473 us; speedup vs baseline: 3.3932x; 1.0641x over previous
//
#include <hip/hip_runtime.h>
#include <math.h>

// CriticBatchNet: NNConv(+edge-net) + GRU x6, Set2Set x6, LSTM head.
// msg[e] = out[src]@W_e[e], W_e[e]=hidden[e]@e_w2+b2
//   => segsum_dst(msg)[m,f] = sum_kd S[m,kd]*Vr[kd,f],
//      S[m,k*32+d] = sum_{e:dst=m} hidden[e,k]*out[src_e,d]
//      S[m,1024+j] = sum_{e:dst=m} out[src_e,j]   (bias rows)
// v8: phase-1 dual-node fused fast path (deg<=16 both: one exposed gather
//     latency per wave, not two); cur kept in packed split-bf16 (curq)
//     written by the GRU epilogue (kills per-edge float->bf16 split);
//     phase-2 2-deep Vr prefetch (first step issued before the barrier).

typedef __attribute__((ext_vector_type(8))) short short8;
typedef __attribute__((ext_vector_type(4))) float f32x4;
typedef __attribute__((ext_vector_type(16))) float f32x16;

#define S_PAD 1060

__device__ __forceinline__ float sigf(float x){ return 1.f/(1.f+expf(-x)); }

__device__ __forceinline__ unsigned packsplit(float v){
  unsigned uv = __float_as_uint(v);
  float res = v - __uint_as_float(uv & 0xFFFF0000u);
  return (uv & 0xFFFF0000u) | (__float_as_uint(res) >> 16);
}

__device__ __forceinline__ short8 ld8(const unsigned short* p){
  return *(const short8*)p;
}

// fused: zero counts/cursor, lin0 (f32 + packed), permW2split
__global__ void k_pre(const float* __restrict__ x, const float* __restrict__ w,
                      const float* __restrict__ b,
                      const float* __restrict__ e_w2, const float* __restrict__ e_b2,
                      float* __restrict__ cur, unsigned* __restrict__ curq,
                      unsigned short* __restrict__ VrT_hi,
                      unsigned short* __restrict__ VrT_lo,
                      int* __restrict__ counts, int* __restrict__ cursor, int N){
  int i = blockIdx.x*blockDim.x + threadIdx.x;
  if (i < N){ counts[i]=0; cursor[i]=0; }
  if (i < N*32){
    int n = i>>5, d = i&31;
    float acc = b[d];
    acc = fmaf(x[n*3+0], w[0*32+d], acc);
    acc = fmaf(x[n*3+1], w[1*32+d], acc);
    acc = fmaf(x[n*3+2], w[2*32+d], acc);
    float v = fmaxf(acc, 0.f);
    cur[i] = v;
    curq[i] = packsplit(v);
  }
  if (i < 1056*32){
    int f = i & 31, kd = i >> 5;
    float v = (kd < 1024) ? e_w2[(kd>>5)*1024 + (kd&31)*32 + f]
                          : e_b2[(kd-1024)*32 + f];
    unsigned ub = __float_as_uint(v);
    float res = v - __uint_as_float(ub & 0xFFFF0000u);
    VrT_hi[f*1056 + kd] = (unsigned short)(ub >> 16);
    VrT_lo[f*1056 + kd] = (unsigned short)(__float_as_uint(res) >> 16);
  }
}

__global__ void k_count(const int* __restrict__ dst, int* __restrict__ counts, int E){
  int i = blockIdx.x*blockDim.x + threadIdx.x;
  if (i < E) atomicAdd(&counts[dst[i]], 1);
}

// 3-stage parallel exclusive scan
__global__ void k_scanA(const int* __restrict__ counts, int* __restrict__ row_off,
                        int* __restrict__ part, int N){
  __shared__ int buf[256];
  int b = blockIdx.x, t = threadIdx.x, base = b*256;
  int v = (base + t < N) ? counts[base + t] : 0;
  buf[t] = v; __syncthreads();
  #pragma unroll
  for (int off = 1; off < 256; off <<= 1){
    int tmp = (t >= off) ? buf[t-off] : 0;
    __syncthreads();
    buf[t] += tmp;
    __syncthreads();
  }
  if (base + t < N) row_off[base + t] = buf[t] - v;
  if (t == 255) part[b] = buf[255];
}

__global__ void k_scanB(int* __restrict__ part, int* __restrict__ row_off,
                        int nch, int N){
  __shared__ int buf[256];
  int t = threadIdx.x;
  int v = (t < nch) ? part[t] : 0;
  buf[t] = v; __syncthreads();
  #pragma unroll
  for (int off = 1; off < 256; off <<= 1){
    int tmp = (t >= off) ? buf[t-off] : 0;
    __syncthreads();
    buf[t] += tmp;
    __syncthreads();
  }
  if (t < nch) part[t] = buf[t] - v;
  if (t == 255) row_off[N] = buf[255];
}

__global__ void k_scanC(int* __restrict__ row_off, const int* __restrict__ part, int N){
  int i = blockIdx.x*256 + threadIdx.x;
  if (i < N) row_off[i] += part[blockIdx.x];
}

__global__ void k_scatter(const int* __restrict__ dst, const int* __restrict__ row_off,
                          int* __restrict__ cursor, int* __restrict__ eid, int E){
  int i = blockIdx.x*blockDim.x + threadIdx.x;
  if (i < E){
    int dn = dst[i];
    int pos = row_off[dn] + atomicAdd(&cursor[dn], 1);
    eid[pos] = i;
  }
}

// fused: hidq[p] = packsplit(relu(ea[eid[p]] @ e_w1 + e_b1)), srcp[p] = src[eid[p]]
__global__ void k_edgeCSR(const int* __restrict__ eid, const int* __restrict__ src,
                          const float* __restrict__ ea, const float* __restrict__ w,
                          const float* __restrict__ b, unsigned* __restrict__ hidq,
                          int* __restrict__ srcp, int E){
  int i = blockIdx.x*blockDim.x + threadIdx.x;
  if (i >= E*32) return;
  int p = i>>5, d = i&31;
  int e = eid[p];
  const float4* ea4 = (const float4*)ea;
  float4 v = ea4[e];
  float acc = b[d];
  acc = fmaf(v.x, w[0*32+d], acc);
  acc = fmaf(v.y, w[1*32+d], acc);
  acc = fmaf(v.z, w[2*32+d], acc);
  acc = fmaf(v.w, w[3*32+d], acc);
  hidq[i] = packsplit(fmaxf(acc, 0.f));
  if (d == 0) srcp[p] = src[e];
}

// Fused per-iteration kernel: 512 threads, 16 nodes (2 per wave in phase 1).
__global__ __launch_bounds__(512) void k_iter(
    const int* __restrict__ row_off, const int* __restrict__ srcp,
    const unsigned* __restrict__ hidq, const unsigned* __restrict__ curq_in,
    const float* __restrict__ cur_in,
    const unsigned short* __restrict__ VrT_hi, const unsigned short* __restrict__ VrT_lo,
    const float* __restrict__ root_w, const float* __restrict__ conv_b,
    const float* __restrict__ wih, const float* __restrict__ whh,
    const float* __restrict__ bih, const float* __restrict__ bhh,
    float* __restrict__ cur_out, unsigned* __restrict__ curq_out, int N){
  __shared__ __align__(16) unsigned s_lds[16*S_PAD];  // packed split-bf16 S rows
  __shared__ float htile[16*32];
  __shared__ float mtile[16*32];
  int nb = blockIdx.x*16;
  int t = threadIdx.x;
  int w = t >> 6, l = t & 63, col = l & 31, half = l >> 5;

  // stage htile early — overlaps phase 1
  {
    int node = t >> 5, f = t & 31;
    int n2 = nb + node;
    htile[t] = (n2 < N) ? cur_in[n2*32 + f] : 0.f;
  }

  // ---- phase 1: 2 nodes per wave ----
  int nA = nb + 2*w;
  int loA = row_off[min(nA, N)],   hiA = row_off[min(nA+1, N)];
  int loB = row_off[min(nA+1, N)], hiB = row_off[min(nA+2, N)];
  int degA = hiA - loA, degB = hiB - loB;
  f32x16 SA = {0.f,0.f,0.f,0.f,0.f,0.f,0.f,0.f,0.f,0.f,0.f,0.f,0.f,0.f,0.f,0.f};
  f32x16 SB = SA;
  float aexA = 0.f, aexB = 0.f;

  if (degA <= 16 && degB <= 16){
    // FAST PATH (>99% of waves): both nodes' load streams in flight together.
    unsigned rh[2][8], ro[2][8];
    int los0 = loA, his0 = hiA, los1 = loB, his1 = hiB;
    #pragma unroll
    for (int j=0;j<8;++j){
      int pA = los0 + 8*half + j; bool vA = pA < his0; int iA = vA ? pA : 0;
      int pB = los1 + 8*half + j; bool vB = pB < his1; int iB = vB ? pB : 0;
      unsigned hA = hidq[iA*32 + col];
      unsigned hB = hidq[iB*32 + col];
      unsigned oA = curq_in[srcp[iA]*32 + col];
      unsigned oB = curq_in[srcp[iB]*32 + col];
      rh[0][j] = vA ? hA : 0u;  ro[0][j] = vA ? oA : 0u;
      rh[1][j] = vB ? hB : 0u;  ro[1][j] = vB ? oB : 0u;
    }
    {
      short8 Ah, Al, Bh, Bl;
      #pragma unroll
      for (int j=0;j<8;++j){
        unsigned h = rh[0][j], o = ro[0][j];
        Ah[j]=(short)(h>>16); Al[j]=(short)(h&0xffffu);
        Bh[j]=(short)(o>>16); Bl[j]=(short)(o&0xffffu);
        aexA += __uint_as_float(o & 0xFFFF0000u) + __uint_as_float(o << 16);
      }
      SA = __builtin_amdgcn_mfma_f32_32x32x16_bf16(Ah, Bh, SA, 0,0,0);
      SA = __builtin_amdgcn_mfma_f32_32x32x16_bf16(Al, Bh, SA, 0,0,0);
      SA = __builtin_amdgcn_mfma_f32_32x32x16_bf16(Ah, Bl, SA, 0,0,0);
    }
    {
      short8 Ah, Al, Bh, Bl;
      #pragma unroll
      for (int j=0;j<8;++j){
        unsigned h = rh[1][j], o = ro[1][j];
        Ah[j]=(short)(h>>16); Al[j]=(short)(h&0xffffu);
        Bh[j]=(short)(o>>16); Bl[j]=(short)(o&0xffffu);
        aexB += __uint_as_float(o & 0xFFFF0000u) + __uint_as_float(o << 16);
      }
      SB = __builtin_amdgcn_mfma_f32_32x32x16_bf16(Ah, Bh, SB, 0,0,0);
      SB = __builtin_amdgcn_mfma_f32_32x32x16_bf16(Al, Bh, SB, 0,0,0);
      SB = __builtin_amdgcn_mfma_f32_32x32x16_bf16(Ah, Bl, SB, 0,0,0);
    }
  } else {
    // SLOW PATH (high-degree): per-node chunk loop
    #pragma unroll
    for (int q = 0; q < 2; ++q){
      int lo2 = q ? loB : loA, hi2 = q ? hiB : hiA;
      f32x16 Sc = {0.f,0.f,0.f,0.f,0.f,0.f,0.f,0.f,0.f,0.f,0.f,0.f,0.f,0.f,0.f,0.f};
      float aex = 0.f;
      for (int p0 = lo2; p0 < hi2; p0 += 16){
        short8 Ah, Al, Bh, Bl;
        #pragma unroll
        for (int j=0;j<8;++j){
          int pp = p0 + 8*half + j;
          bool val = pp < hi2;
          int idx = val ? pp : 0;
          unsigned hp = hidq[idx*32 + col];
          unsigned o  = curq_in[srcp[idx]*32 + col];
          hp = val ? hp : 0u;
          o  = val ? o  : 0u;
          Ah[j] = (short)(hp >> 16);
          Al[j] = (short)(hp & 0xffffu);
          Bh[j] = (short)(o >> 16);
          Bl[j] = (short)(o & 0xffffu);
          aex += __uint_as_float(o & 0xFFFF0000u) + __uint_as_float(o << 16);
        }
        Sc = __builtin_amdgcn_mfma_f32_32x32x16_bf16(Ah, Bh, Sc, 0,0,0);
        Sc = __builtin_amdgcn_mfma_f32_32x32x16_bf16(Al, Bh, Sc, 0,0,0);
        Sc = __builtin_amdgcn_mfma_f32_32x32x16_bf16(Ah, Bl, Sc, 0,0,0);
      }
      if (q == 0){ SA = Sc; aexA = aex; } else { SB = Sc; aexB = aex; }
    }
  }
  // write packed split S rows: C row=(i&3)+8*(i>>2)+4*half (k), col=d
  {
    unsigned* sp = &s_lds[(2*w)*S_PAD];
    #pragma unroll
    for (int i=0;i<16;++i){
      int k = (i&3) + 8*(i>>2) + 4*half;
      sp[k*32 + col] = packsplit(SA[i]);
    }
    aexA += __shfl_xor(aexA, 32, 64);
    if (l < 32) sp[1024 + l] = packsplit(aexA);
    unsigned* sp2 = &s_lds[(2*w+1)*S_PAD];
    #pragma unroll
    for (int i=0;i<16;++i){
      int k = (i&3) + 8*(i>>2) + 4*half;
      sp2[k*32 + col] = packsplit(SB[i]);
    }
    aexB += __shfl_xor(aexB, 32, 64);
    if (l < 32) sp2[1024 + l] = packsplit(aexB);
  }

  // ---- phase 2: C[m][f] = sum_kd S[m][kd]*Vr[kd][f], 33 K-steps / 8 waves ----
  int fc = l & 15, hq = l >> 4;
  const unsigned* arow = &s_lds[fc*S_PAD];
  const unsigned short* bh0p = VrT_hi + fc*1056;
  const unsigned short* bl0p = VrT_lo + fc*1056;
  const unsigned short* bh1p = VrT_hi + (16+fc)*1056;
  const unsigned short* bl1p = VrT_lo + (16+fc)*1056;
  f32x4 acc0 = {0.f,0.f,0.f,0.f}, acc1 = {0.f,0.f,0.f,0.f};
  int s_lo = (w*33) >> 3, s_hi = ((w+1)*33) >> 3;
  // issue first K-step's B loads BEFORE the barrier (they don't touch LDS)
  int kb0 = s_lo*32 + hq*8;
  short8 bh0c = ld8(bh0p + kb0), bl0c = ld8(bl0p + kb0);
  short8 bh1c = ld8(bh1p + kb0), bl1c = ld8(bl1p + kb0);
  __syncthreads();
  for (int st = s_lo; st < s_hi; ++st){
    short8 bh0n, bl0n, bh1n, bl1n;
    bool more = (st + 1) < s_hi;
    if (more){
      int kb2 = (st+1)*32 + hq*8;
      bh0n = ld8(bh0p + kb2); bl0n = ld8(bl0p + kb2);
      bh1n = ld8(bh1p + kb2); bl1n = ld8(bl1p + kb2);
    }
    int kb = st*32 + hq*8;
    const uint4* ap = (const uint4*)(arow + kb);
    uint4 ua = ap[0], ub = ap[1];
    short8 Ah, Al;
    Ah[0]=(short)(ua.x>>16); Al[0]=(short)(ua.x & 0xffffu);
    Ah[1]=(short)(ua.y>>16); Al[1]=(short)(ua.y & 0xffffu);
    Ah[2]=(short)(ua.z>>16); Al[2]=(short)(ua.z & 0xffffu);
    Ah[3]=(short)(ua.w>>16); Al[3]=(short)(ua.w & 0xffffu);
    Ah[4]=(short)(ub.x>>16); Al[4]=(short)(ub.x & 0xffffu);
    Ah[5]=(short)(ub.y>>16); Al[5]=(short)(ub.y & 0xffffu);
    Ah[6]=(short)(ub.z>>16); Al[6]=(short)(ub.z & 0xffffu);
    Ah[7]=(short)(ub.w>>16); Al[7]=(short)(ub.w & 0xffffu);
    acc0 = __builtin_amdgcn_mfma_f32_16x16x32_bf16(Ah, bh0c, acc0, 0,0,0);
    acc0 = __builtin_amdgcn_mfma_f32_16x16x32_bf16(Al, bh0c, acc0, 0,0,0);
    acc0 = __builtin_amdgcn_mfma_f32_16x16x32_bf16(Ah, bl0c, acc0, 0,0,0);
    acc1 = __builtin_amdgcn_mfma_f32_16x16x32_bf16(Ah, bh1c, acc1, 0,0,0);
    acc1 = __builtin_amdgcn_mfma_f32_16x16x32_bf16(Al, bh1c, acc1, 0,0,0);
    acc1 = __builtin_amdgcn_mfma_f32_16x16x32_bf16(Ah, bl1c, acc1, 0,0,0);
    if (more){ bh0c = bh0n; bl0c = bl0n; bh1c = bh1n; bl1c = bl1n; }
  }
  __syncthreads();                       // all s_lds reads done
  float* pbuf = (float*)s_lds;           // reuse: [w][m(16)][32]
  #pragma unroll
  for (int i=0;i<4;++i){
    int m = hq*4 + i;                    // C row = node (all 16 valid)
    pbuf[(w*16 + m)*32 + fc]      = acc0[i];
    pbuf[(w*16 + m)*32 + 16 + fc] = acc1[i];
  }
  __syncthreads();

  // ---- epilogue: reduce partials, root+relu -> m, then GRU ----
  int node = t >> 5, f = t & 31;
  int n2 = nb + node;
  if (n2 < N){
    float msum = 0.f;
    #pragma unroll
    for (int w2=0; w2<8; ++w2) msum += pbuf[(w2*16 + node)*32 + f];
    float deg = (float)max(row_off[n2+1] - row_off[n2], 1);
    float rt = 0.f;
    #pragma unroll
    for (int k=0;k<32;++k) rt = fmaf(htile[node*32+k], root_w[k*32+f], rt);
    mtile[node*32 + f] = fmaxf(msum/deg + rt + conv_b[f], 0.f);
  }
  __syncthreads();
  if (n2 < N){
    float gr = bih[f], gz = bih[32+f], gn = bih[64+f];
    float hr = bhh[f], hz = bhh[32+f], hn = bhh[64+f];
    const float* mm = &mtile[node*32];
    const float* hh = &htile[node*32];
    #pragma unroll
    for (int k=0;k<32;++k){
      float mv = mm[k], hv = hh[k];
      gr = fmaf(mv, wih[k*96 + f],      gr);
      gz = fmaf(mv, wih[k*96 + 32 + f], gz);
      gn = fmaf(mv, wih[k*96 + 64 + f], gn);
      hr = fmaf(hv, whh[k*96 + f],      hr);
      hz = fmaf(hv, whh[k*96 + 32 + f], hz);
      hn = fmaf(hv, whh[k*96 + 64 + f], hn);
    }
    float r = sigf(gr + hr);
    float z = sigf(gz + hz);
    float nn2 = tanhf(gn + r*hn);
    float nv = (1.f - z)*nn2 + z*hh[f];
    cur_out[n2*32 + f] = nv;
    curq_out[n2*32 + f] = packsplit(nv);
  }
}

// Set2Set x6 + memory LSTM + FC head; one 512-thread block per graph.
// All per-iteration operands (cur slice, LSTM weights) live in LDS.
#define S2S_CAP 480
__global__ __launch_bounds__(512) void k_s2s(
    const float* __restrict__ cur,
    const float* __restrict__ wi, const float* __restrict__ wh, const float* __restrict__ sb,
    const float* __restrict__ mwi, const float* __restrict__ mwh, const float* __restrict__ mb,
    const float* __restrict__ hx, const float* __restrict__ cx,
    const float* __restrict__ f1w, const float* __restrict__ f1b,
    const float* __restrict__ f2w, const float* __restrict__ f2b,
    float* __restrict__ out, int N, int G){
  int g = blockIdx.x, t = threadIdx.x;
  int lo = (int)(((long long)g*N + G - 1)/G);
  int hi = (int)(((long long)(g+1)*N + G - 1)/G);
  int cnt = hi - lo;                     // <= S2S_CAP (469 at N=15000,G=32)
  __shared__ float curL[S2S_CAP*33];     // 63.4 KB
  __shared__ float wiL[96*128];          // 49.2 KB: rows 0..63 = wi, 64..95 = wh
  __shared__ float ebuf[S2S_CAP];
  __shared__ float qh[96];               // [0..63]=q_star, [64..95]=hs
  __shared__ float csS[32];
  __shared__ float gbuf[128];
  __shared__ float pbuf4[4][128];
  __shared__ float redr[8*32];
  __shared__ float smax[8], ssum[8];
  __shared__ float bmaxS, bsumS;
  __shared__ float hnew[32], f1o[32];
  for (int i = t; i < cnt*32; i += 512){
    int p = i >> 5, d2 = i & 31;
    curL[p*33 + d2] = cur[(size_t)(lo + p)*32 + d2];
  }
  for (int i = t; i < 96*128; i += 512){
    int j = i >> 7, o = i & 127;
    wiL[i] = (j < 64) ? wi[j*128 + o] : wh[(j-64)*128 + o];
  }
  if (t < 96) qh[t] = 0.f;
  if (t < 32) csS[t] = 0.f;
  __syncthreads();
  int wv = t >> 6, l = t & 63, d = l & 31, halfw = l >> 5;
  int p0 = wv*2 + halfw;
  for (int it = 0; it < 6; ++it){
    {
      int o = t & 127, part = t >> 7;
      const float* wp = &wiL[part*24*128 + o];
      const float* qp = &qh[part*24];
      float a = 0.f;
      #pragma unroll
      for (int jj=0;jj<24;++jj) a = fmaf(qp[jj], wp[jj*128], a);
      pbuf4[part][o] = a;
    }
    __syncthreads();
    if (t < 128) gbuf[t] = pbuf4[0][t]+pbuf4[1][t]+pbuf4[2][t]+pbuf4[3][t] + sb[t];
    __syncthreads();
    if (t < 32){
      float c = sigf(gbuf[32+t])*csS[t] + sigf(gbuf[t])*tanhf(gbuf[64+t]);
      csS[t] = c;
      qh[64+t] = sigf(gbuf[96+t])*tanhf(c);
    }
    __syncthreads();
    float lmax = -3.4e38f;
    for (int p = t; p < cnt; p += 512){
      float acc = 0.f;
      #pragma unroll
      for (int d2=0; d2<32; ++d2) acc = fmaf(curL[p*33 + d2], qh[64+d2], acc);
      ebuf[p] = acc;
      lmax = fmaxf(lmax, acc);
    }
    #pragma unroll
    for (int o2 = 1; o2 < 64; o2 <<= 1) lmax = fmaxf(lmax, __shfl_xor(lmax, o2, 64));
    if (l == 0) smax[wv] = lmax;
    __syncthreads();
    if (t == 0){ float mm = smax[0]; for (int i=1;i<8;++i) mm = fmaxf(mm, smax[i]); bmaxS = mm; }
    __syncthreads();
    float bmax = bmaxS;
    float lsum = 0.f;
    for (int p = t; p < cnt; p += 512){
      float a = expf(ebuf[p] - bmax);
      ebuf[p] = a;
      lsum += a;
    }
    #pragma unroll
    for (int o2 = 1; o2 < 64; o2 <<= 1) lsum += __shfl_xor(lsum, o2, 64);
    if (l == 0) ssum[wv] = lsum;
    __syncthreads();
    if (t == 0){ float s2 = 0.f; for (int i=0;i<8;++i) s2 += ssum[i]; bsumS = s2; }
    __syncthreads();
    float racc = 0.f;
    for (int p = p0; p < cnt; p += 16)
      racc = fmaf(ebuf[p], curL[p*33 + d], racc);
    racc += __shfl_xor(racc, 32, 64);
    if (l < 32) redr[wv*32 + l] = racc;
    __syncthreads();
    if (t < 32){
      float rsum = 0.f;
      #pragma unroll
      for (int w2=0; w2<8; ++w2) rsum += redr[w2*32 + t];
      qh[t] = qh[64+t];
      qh[32 + t] = rsum / bsumS;
    }
    __syncthreads();
  }
  if (t < 128){
    float acc = mb[t];
    for (int j=0;j<64;++j) acc = fmaf(qh[j], mwi[j*128+t], acc);
    for (int j=0;j<32;++j) acc = fmaf(hx[g*32+j], mwh[j*128+t], acc);
    gbuf[t] = acc;
  }
  __syncthreads();
  if (t < 32){
    float c = sigf(gbuf[32+t])*cx[g*32+t] + sigf(gbuf[t])*tanhf(gbuf[64+t]);
    float h = sigf(gbuf[96+t])*tanhf(c);
    out[G + g*32 + t] = h;
    out[G + G*32 + g*32 + t] = c;
    hnew[t] = h;
  }
  __syncthreads();
  if (t < 32){
    float acc = f1b[t];
    #pragma unroll
    for (int k=0;k<32;++k) acc = fmaf(hnew[k], f1w[k*32+t], acc);
    f1o[t] = fmaxf(acc, 0.f);
  }
  __syncthreads();
  if (t == 0){
    float acc = f2b[0];
    #pragma unroll
    for (int k=0;k<32;++k) acc = fmaf(f1o[k], f2w[k], acc);
    out[g] = acc;
  }
}

extern "C" void kernel_launch(void* const* d_in, const int* in_sizes, int n_in,
                              void* d_out, int out_size, void* d_ws, size_t ws_size,
                              hipStream_t stream) {
  const float* x      = (const float*)d_in[0];
  const float* ea     = (const float*)d_in[1];
  const float* hx     = (const float*)d_in[2];
  const float* cx     = (const float*)d_in[3];
  const float* lin0_w = (const float*)d_in[4];
  const float* lin0_b = (const float*)d_in[5];
  const float* e_w1   = (const float*)d_in[6];
  const float* e_b1   = (const float*)d_in[7];
  const float* e_w2   = (const float*)d_in[8];
  const float* e_b2   = (const float*)d_in[9];
  const float* root_w = (const float*)d_in[10];
  const float* conv_b = (const float*)d_in[11];
  const float* g_wih  = (const float*)d_in[12];
  const float* g_whh  = (const float*)d_in[13];
  const float* g_bih  = (const float*)d_in[14];
  const float* g_bhh  = (const float*)d_in[15];
  const float* s_wi   = (const float*)d_in[16];
  const float* s_wh   = (const float*)d_in[17];
  const float* s_b    = (const float*)d_in[18];
  const float* m_wi   = (const float*)d_in[19];
  const float* m_wh   = (const float*)d_in[20];
  const float* m_b    = (const float*)d_in[21];
  const float* f1w    = (const float*)d_in[22];
  const float* f1b    = (const float*)d_in[23];
  const float* f2w    = (const float*)d_in[24];
  const float* f2b    = (const float*)d_in[25];
  const int*   eidx   = (const int*)d_in[26];
  int N = in_sizes[0]/3;
  int E = in_sizes[1]/4;
  int G = in_sizes[2]/32;
  const int* srcI = eidx;
  const int* dstI = eidx + E;
  float* outF = (float*)d_out;

  char* wbase = (char*)d_ws; size_t off = 0;
  auto carve = [&](size_t nbytes)->char*{
    char* p = wbase + off; off = (off + nbytes + 255) & ~(size_t)255; return p;
  };
  float* cur0    = (float*)carve((size_t)N*32*4);
  float* cur1    = (float*)carve((size_t)N*32*4);
  unsigned* curq0 = (unsigned*)carve((size_t)N*32*4);
  unsigned* curq1 = (unsigned*)carve((size_t)N*32*4);
  unsigned* hidq = (unsigned*)carve((size_t)E*32*4);
  unsigned short* VrT_hi = (unsigned short*)carve((size_t)1056*32*2);
  unsigned short* VrT_lo = (unsigned short*)carve((size_t)1056*32*2);
  int*   counts  = (int*)carve((size_t)N*4);
  int*   cursor  = (int*)carve((size_t)N*4);
  int*   row_off = (int*)carve((size_t)(N+1)*4);
  int*   eid     = (int*)carve((size_t)E*4);
  int*   srcp    = (int*)carve((size_t)E*4);
  int*   part    = (int*)carve((size_t)256*4);
  (void)ws_size; (void)n_in; (void)out_size;

  int nch = (N + 255)/256;

  // phase A: fused pre (init+lin0+W2 split), CSR build with parallel scan
  k_pre<<<(N*32+255)/256, 256, 0, stream>>>(x, lin0_w, lin0_b, e_w2, e_b2,
                                            cur0, curq0, VrT_hi, VrT_lo,
                                            counts, cursor, N);
  k_count<<<(E+255)/256, 256, 0, stream>>>(dstI, counts, E);
  k_scanA<<<nch, 256, 0, stream>>>(counts, row_off, part, N);
  k_scanB<<<1, 256, 0, stream>>>(part, row_off, nch, N);
  k_scanC<<<nch, 256, 0, stream>>>(row_off, part, N);
  k_scatter<<<(E+255)/256, 256, 0, stream>>>(dstI, row_off, cursor, eid, E);
  k_edgeCSR<<<(E*32+255)/256, 256, 0, stream>>>(eid, srcI, ea, e_w1, e_b1, hidq, srcp, E);

  // phase B: 6 fused message-passing + GRU iterations (ping-pong cur/curq)
  float* cin = cur0; float* cout = cur1;
  unsigned* qin = curq0; unsigned* qout = curq1;
  for (int it = 0; it < 6; ++it){
    k_iter<<<(N+15)/16, 512, 0, stream>>>(row_off, srcp, hidq, qin, cin,
                                          VrT_hi, VrT_lo,
                                          root_w, conv_b, g_wih, g_whh, g_bih, g_bhh,
                                          cout, qout, N);
    float* tf = cin; cin = cout; cout = tf;
    unsigned* tq = qin; qin = qout; qout = tq;
  }

  // phase C+D: Set2Set x6 + memory LSTM + FC head
  k_s2s<<<G, 512, 0, stream>>>(cin, s_wi, s_wh, s_b, m_wi, m_wh, m_b,
                               hx, cx, f1w, f1b, f2w, f2b, outF, N, G);
}